// Round 2
// baseline (953.756 us; speedup 1.0000x reference)
//
#include <hip/hip_runtime.h>
#include <hip/hip_bf16.h>
#include <cstdint>
#include <cstddef>

#define NNODES 20000
#define MNB    16
#define NFEAT  500
#define OUTC   656

__device__ __forceinline__ float bf2f(unsigned int h) {
    union { unsigned int u; float f; } v; v.u = h << 16; return v.f;
}
__device__ __forceinline__ unsigned short f2bf(float f) {
    union { float f; unsigned int u; } v; v.f = f;
    unsigned int u = v.u;
    u += 0x7FFFu + ((u >> 16) & 1u);   // RNE
    return (unsigned short)(u >> 16);
}

// ---------------- dtype probe: even-index shorts of fp32 data have uniform-random
// exponent fields (~16% in [100,140]); of bf16 data they are real bf16s (~100%).
__global__ __launch_bounds__(64) void detect_kernel(const unsigned short* __restrict__ fx,
                                                    int* __restrict__ flag) {
    const int tid = threadIdx.x;
    const unsigned short s = fx[2 * tid];
    const int e = (s >> 7) & 0xFF;
    const bool ok = (e >= 100 && e <= 140);
    const unsigned long long m = __ballot(ok);
    if (tid == 0) *flag = (__popcll(m) >= 32) ? 1 : 0;
}

// ---------------- convert all weights/biases to one fp32 blob in ws
struct WPtrs { const void* p[12]; };

__global__ __launch_bounds__(256) void convert_weights(WPtrs ptrs, const int* __restrict__ flag,
                                                       float* __restrict__ outb) {
    constexpr int SN[12] = {64000,128,14336,112,10752,96,7680,80,5120,64,3072,48};
    constexpr int SO[12] = {0,64000,64128,78464,78576,89328,89424,97104,97184,102304,102368,105440};
    constexpr int TOT = 105488;
    const int i = blockIdx.x * 256 + threadIdx.x;
    if (i >= TOT) return;
    const bool isbf = (*flag != 0);
    int seg = 0, local = i;
#pragma unroll
    for (int s = 0; s < 12; ++s) {
        if (i >= SO[s] && i < SO[s] + SN[s]) { seg = s; local = i - SO[s]; }
    }
    const void* src = ptrs.p[seg];
    float v;
    if (isbf) v = bf2f(((const unsigned short*)src)[local]);
    else      v = ((const float*)src)[local];
    outb[i] = v;
}

// ---------------- PCA: relu(feature @ pca_w.T + b) -> out[:,0:128] and normalized fp32 xn
__global__ __launch_bounds__(128) void pca_kernel(
    const void* __restrict__ feat_raw,
    const float* __restrict__ wf,
    const float* __restrict__ bf_,
    const int* __restrict__ flag,
    float* __restrict__ xn,
    void* __restrict__ out_raw)
{
    __shared__ float sf[8][NFEAT];
    __shared__ float sy[8][129];
    __shared__ float sinv[8][8];
    const int tid = threadIdx.x;
    const int r0 = blockIdx.x * 8;
    const bool isbf = (*flag != 0);

    if (isbf) {
        const unsigned short* feat = (const unsigned short*)feat_raw;
        for (int r = 0; r < 8; ++r)
            for (int c = tid; c < NFEAT; c += 128)
                sf[r][c] = bf2f(feat[(size_t)(r0 + r) * NFEAT + c]);
    } else {
        const float* feat = (const float*)feat_raw;
        for (int r = 0; r < 8; ++r)
            for (int c = tid; c < NFEAT; c += 128)
                sf[r][c] = feat[(size_t)(r0 + r) * NFEAT + c];
    }
    __syncthreads();

    const int col = tid;
    float acc[8];
#pragma unroll
    for (int r = 0; r < 8; ++r) acc[r] = 0.f;
    const float* wrow = wf + (size_t)col * NFEAT;
    for (int k = 0; k < NFEAT; k += 4) {
        const float4 w4 = *(const float4*)(wrow + k);
#pragma unroll
        for (int r = 0; r < 8; ++r) {
            const float4 f = *(const float4*)&sf[r][k];
            acc[r] = fmaf(w4.x, f.x, acc[r]);
            acc[r] = fmaf(w4.y, f.y, acc[r]);
            acc[r] = fmaf(w4.z, f.z, acc[r]);
            acc[r] = fmaf(w4.w, f.w, acc[r]);
        }
    }
    const float bb = bf_[col];
    float yv[8];
#pragma unroll
    for (int r = 0; r < 8; ++r) {
        yv[r] = fmaxf(acc[r] + bb, 0.f);
        sy[r][col] = yv[r];
    }
    if (isbf) {
        unsigned short* ob = (unsigned short*)out_raw;
#pragma unroll
        for (int r = 0; r < 8; ++r) ob[(size_t)(r0 + r) * OUTC + col] = f2bf(yv[r]);
    } else {
        float* of = (float*)out_raw;
#pragma unroll
        for (int r = 0; r < 8; ++r) of[(size_t)(r0 + r) * OUTC + col] = yv[r];
    }
    __syncthreads();
    if (tid < 64) {
        const int r = tid >> 3, cap = tid & 7;
        float ss = 0.f;
#pragma unroll
        for (int d = 0; d < 16; ++d) { const float v = sy[r][cap * 16 + d]; ss = fmaf(v, v, ss); }
        sinv[r][cap] = 1.0f / fmaxf(sqrtf(ss), 1e-12f);
    }
    __syncthreads();
#pragma unroll
    for (int r = 0; r < 8; ++r)
        xn[(size_t)(r0 + r) * 128 + col] = sy[r][col] * sinv[r][col >> 4];
}

// ---------------- per-layer linear (fp32 weights from ws blob) + per-capsule normalize
template<int FIN, int FOUT>
__global__ __launch_bounds__(128) void linear_norm_kernel(
    const float* __restrict__ xin,
    const float* __restrict__ w,
    const float* __restrict__ bias,
    float* __restrict__ xn)
{
    __shared__ float sx[FIN];
    __shared__ float sy[FOUT];
    __shared__ float sinv[FOUT / 16];
    const int tid = threadIdx.x;
    const int node = blockIdx.x;
    if (tid < FIN) sx[tid] = xin[(size_t)node * FIN + tid];
    __syncthreads();
    if (tid < FOUT) {
        float acc = bias[tid];
        const float* wrow = w + (size_t)tid * FIN;
#pragma unroll 4
        for (int k = 0; k < FIN; k += 4) {
            const float4 w4 = *(const float4*)(wrow + k);
            acc = fmaf(w4.x, sx[k],     acc);
            acc = fmaf(w4.y, sx[k + 1], acc);
            acc = fmaf(w4.z, sx[k + 2], acc);
            acc = fmaf(w4.w, sx[k + 3], acc);
        }
        sy[tid] = acc;
    }
    __syncthreads();
    if (tid < FOUT / 16) {
        float ss = 0.f;
#pragma unroll
        for (int d = 0; d < 16; ++d) { const float v = sy[tid * 16 + d]; ss = fmaf(v, v, ss); }
        sinv[tid] = 1.0f / fmaxf(sqrtf(ss), 1e-12f);
    }
    __syncthreads();
    if (tid < FOUT) xn[(size_t)node * FOUT + tid] = sy[tid] * sinv[tid >> 4];
}

// ---------------- routing: one wave per node, z staged in LDS, 5 iterations on-chip.
template<int K>
__global__ __launch_bounds__(64) void routing_kernel(
    const float* __restrict__ xn,
    const int* __restrict__ nb,
    float* __restrict__ xout,
    void* __restrict__ out_raw,
    const int* __restrict__ flag,
    const int coloff)
{
    constexpr int KD16 = K * 16;
    constexpr int ZS = KD16 + 4;          // +4 floats pad -> 2-way banks (free)
    __shared__ float z[16 * ZS];
    __shared__ float u[KD16];
    __shared__ float xs[KD16];
    __shared__ float p[16 * K];
    __shared__ int nid[16];
    const int tid = threadIdx.x;
    const int node = blockIdx.x;
    const bool isbf = (*flag != 0);

    if (tid < 16) nid[tid] = nb[(size_t)node * 16 + tid];
    for (int idx = tid; idx < KD16; idx += 64) {
        const float v = xn[(size_t)node * KD16 + idx];
        xs[idx] = v; u[idx] = v;
    }
    __syncthreads();
    for (int j = 0; j < 16; ++j) {
        const float* src = xn + (size_t)nid[j] * KD16;
        for (int c = tid; c < KD16; c += 64) z[j * ZS + c] = src[c];
    }
    __syncthreads();

    for (int t = 0; t < 5; ++t) {
        // p[j][kk] = dot(z[j,kk,:], u[kk,:])
        for (int idx = tid; idx < 16 * K; idx += 64) {
            const int kk = idx >> 4, j = idx & 15;
            const float4* zp = (const float4*)&z[j * ZS + kk * 16];
            const float4* up = (const float4*)&u[kk * 16];
            float s = 0.f;
#pragma unroll
            for (int g = 0; g < 4; ++g) {
                const float4 a = zp[g], b = up[g];
                s += a.x * b.x + a.y * b.y + a.z * b.z + a.w * b.w;
            }
            p[j * K + kk] = s;
        }
        __syncthreads();
        // softmax over capsules, per neighbor j
        if (tid < 16) {
            float vals[K];
            float mx = -1e30f;
#pragma unroll
            for (int kk = 0; kk < K; ++kk) { vals[kk] = p[tid * K + kk]; mx = fmaxf(mx, vals[kk]); }
            float s = 0.f;
#pragma unroll
            for (int kk = 0; kk < K; ++kk) { vals[kk] = __expf(vals[kk] - mx); s += vals[kk]; }
            const float inv = 1.0f / s;
#pragma unroll
            for (int kk = 0; kk < K; ++kk) p[tid * K + kk] = vals[kk] * inv;
        }
        __syncthreads();
        // u[kk][d] = sum_j p[j][kk] * z[j][kk][d] + xs[kk][d]  (lane = kk*8 + dpair)
        if (tid < K * 8) {
            const int kk = tid >> 3, dp = tid & 7, base = kk * 16 + dp * 2;
            float a0 = xs[base], a1 = xs[base + 1];
#pragma unroll
            for (int j = 0; j < 16; ++j) {
                const float pj = p[j * K + kk];
                const float2 zz = *(const float2*)&z[j * ZS + base];
                a0 = fmaf(pj, zz.x, a0);
                a1 = fmaf(pj, zz.y, a1);
            }
            if (t < 4) {
                float ss = a0 * a0 + a1 * a1;
                ss += __shfl_xor(ss, 1);
                ss += __shfl_xor(ss, 2);
                ss += __shfl_xor(ss, 4);
                const float inv = 1.0f / fmaxf(sqrtf(ss), 1e-12f);
                a0 *= inv; a1 *= inv;
                u[base] = a0; u[base + 1] = a1;
            } else {
                a0 = fmaxf(a0, 0.f); a1 = fmaxf(a1, 0.f);
                xout[(size_t)node * KD16 + base]     = a0;
                xout[(size_t)node * KD16 + base + 1] = a1;
                if (isbf) {
                    unsigned short* ob = (unsigned short*)out_raw;
                    const unsigned int packed = ((unsigned int)f2bf(a1) << 16) | (unsigned int)f2bf(a0);
                    *(unsigned int*)&ob[(size_t)node * OUTC + coloff + base] = packed;
                } else {
                    float* of = (float*)out_raw;
                    of[(size_t)node * OUTC + coloff + base]     = a0;
                    of[(size_t)node * OUTC + coloff + base + 1] = a1;
                }
            }
        }
        __syncthreads();
    }
}

extern "C" void kernel_launch(void* const* d_in, const int* in_sizes, int n_in,
                              void* d_out, int out_size, void* d_ws, size_t ws_size,
                              hipStream_t stream) {
    const int* nbid = (const int*)d_in[1];

    int*   flag  = (int*)d_ws;
    float* wblob = (float*)((char*)d_ws + 16);
    float* xn    = (float*)((char*)d_ws + (512 << 10));
    float* xc    = xn + (size_t)NNODES * 128;

    // fp32 weight blob offsets
    float* pw = wblob +      0; float* pb = wblob +  64000;
    float* w1 = wblob +  64128; float* b1 = wblob +  78464;
    float* w2 = wblob +  78576; float* b2 = wblob +  89328;
    float* w3 = wblob +  89424; float* b3 = wblob +  97104;
    float* w4 = wblob +  97184; float* b4 = wblob + 102304;
    float* w5 = wblob + 102368; float* b5 = wblob + 105440;

    hipLaunchKernelGGL(detect_kernel, dim3(1), dim3(64), 0, stream,
                       (const unsigned short*)d_in[0], flag);

    WPtrs wp;
    for (int i = 0; i < 12; ++i) wp.p[i] = d_in[i + 2];
    hipLaunchKernelGGL(convert_weights, dim3(413), dim3(256), 0, stream, wp, flag, wblob);

    hipLaunchKernelGGL(pca_kernel, dim3(NNODES / 8), dim3(128), 0, stream,
                       d_in[0], pw, pb, flag, xn, d_out);

    hipLaunchKernelGGL((routing_kernel<8>), dim3(NNODES), dim3(64), 0, stream,
                       xn, nbid, xc, d_out, flag, 128);
    hipLaunchKernelGGL((linear_norm_kernel<128, 112>), dim3(NNODES), dim3(128), 0, stream,
                       xc, w1, b1, xn);

    hipLaunchKernelGGL((routing_kernel<7>), dim3(NNODES), dim3(64), 0, stream,
                       xn, nbid, xc, d_out, flag, 256);
    hipLaunchKernelGGL((linear_norm_kernel<112, 96>), dim3(NNODES), dim3(128), 0, stream,
                       xc, w2, b2, xn);

    hipLaunchKernelGGL((routing_kernel<6>), dim3(NNODES), dim3(64), 0, stream,
                       xn, nbid, xc, d_out, flag, 368);
    hipLaunchKernelGGL((linear_norm_kernel<96, 80>), dim3(NNODES), dim3(128), 0, stream,
                       xc, w3, b3, xn);

    hipLaunchKernelGGL((routing_kernel<5>), dim3(NNODES), dim3(64), 0, stream,
                       xn, nbid, xc, d_out, flag, 464);
    hipLaunchKernelGGL((linear_norm_kernel<80, 64>), dim3(NNODES), dim3(128), 0, stream,
                       xc, w4, b4, xn);

    hipLaunchKernelGGL((routing_kernel<4>), dim3(NNODES), dim3(64), 0, stream,
                       xn, nbid, xc, d_out, flag, 544);
    hipLaunchKernelGGL((linear_norm_kernel<64, 48>), dim3(NNODES), dim3(128), 0, stream,
                       xc, w5, b5, xn);

    hipLaunchKernelGGL((routing_kernel<3>), dim3(NNODES), dim3(64), 0, stream,
                       xn, nbid, xc, d_out, flag, 608);
}

// Round 3
// 801.769 us; speedup vs baseline: 1.1896x; 1.1896x over previous
//
#include <hip/hip_runtime.h>
#include <hip/hip_bf16.h>
#include <cstdint>
#include <cstddef>

#define NNODES 20000
#define MNB    16
#define NFEAT  500
#define OUTC   656

__device__ __forceinline__ float bf2f(unsigned int h) {
    union { unsigned int u; float f; } v; v.u = h << 16; return v.f;
}
__device__ __forceinline__ unsigned short f2bf(float f) {
    union { float f; unsigned int u; } v; v.f = f;
    unsigned int u = v.u;
    u += 0x7FFFu + ((u >> 16) & 1u);   // RNE
    return (unsigned short)(u >> 16);
}

// ---------------- dtype probe: even-index shorts of fp32 data have uniform-random
// exponent fields (~16% in [100,140]); of bf16 data they are real bf16s (~100%).
__global__ __launch_bounds__(64) void detect_kernel(const unsigned short* __restrict__ fx,
                                                    int* __restrict__ flag) {
    const int tid = threadIdx.x;
    const unsigned short s = fx[2 * tid];
    const int e = (s >> 7) & 0xFF;
    const bool ok = (e >= 100 && e <= 140);
    const unsigned long long m = __ballot(ok);
    if (tid == 0) *flag = (__popcll(m) >= 32) ? 1 : 0;
}

// ---------------- convert all weights/biases to one fp32 blob in ws
struct WPtrs { const void* p[12]; };

__global__ __launch_bounds__(256) void convert_weights(WPtrs ptrs, const int* __restrict__ flag,
                                                       float* __restrict__ outb) {
    constexpr int SN[12] = {64000,128,14336,112,10752,96,7680,80,5120,64,3072,48};
    constexpr int SO[12] = {0,64000,64128,78464,78576,89328,89424,97104,97184,102304,102368,105440};
    constexpr int TOT = 105488;
    const int i = blockIdx.x * 256 + threadIdx.x;
    if (i >= TOT) return;
    const bool isbf = (*flag != 0);
    int seg = 0, local = i;
#pragma unroll
    for (int s = 0; s < 12; ++s) {
        if (i >= SO[s] && i < SO[s] + SN[s]) { seg = s; local = i - SO[s]; }
    }
    const void* src = ptrs.p[seg];
    float v;
    if (isbf) v = bf2f(((const unsigned short*)src)[local]);
    else      v = ((const float*)src)[local];
    outb[i] = v;
}

// ---------------- PCA: relu(feature @ pca_w.T + b) -> out[:,0:128] and normalized fp32 xn
__global__ __launch_bounds__(128) void pca_kernel(
    const void* __restrict__ feat_raw,
    const float* __restrict__ wf,
    const float* __restrict__ bf_,
    const int* __restrict__ flag,
    float* __restrict__ xn,
    void* __restrict__ out_raw)
{
    __shared__ float sf[8][NFEAT];
    __shared__ float sy[8][129];
    __shared__ float sinv[8][8];
    const int tid = threadIdx.x;
    const int r0 = blockIdx.x * 8;
    const bool isbf = (*flag != 0);

    if (isbf) {
        const unsigned short* feat = (const unsigned short*)feat_raw;
        for (int r = 0; r < 8; ++r)
            for (int c = tid; c < NFEAT; c += 128)
                sf[r][c] = bf2f(feat[(size_t)(r0 + r) * NFEAT + c]);
    } else {
        const float* feat = (const float*)feat_raw;
        for (int r = 0; r < 8; ++r)
            for (int c = tid; c < NFEAT; c += 128)
                sf[r][c] = feat[(size_t)(r0 + r) * NFEAT + c];
    }
    __syncthreads();

    const int col = tid;
    float acc[8];
#pragma unroll
    for (int r = 0; r < 8; ++r) acc[r] = 0.f;
    const float* wrow = wf + (size_t)col * NFEAT;
    for (int k = 0; k < NFEAT; k += 4) {
        const float4 w4 = *(const float4*)(wrow + k);
#pragma unroll
        for (int r = 0; r < 8; ++r) {
            const float4 f = *(const float4*)&sf[r][k];
            acc[r] = fmaf(w4.x, f.x, acc[r]);
            acc[r] = fmaf(w4.y, f.y, acc[r]);
            acc[r] = fmaf(w4.z, f.z, acc[r]);
            acc[r] = fmaf(w4.w, f.w, acc[r]);
        }
    }
    const float bb = bf_[col];
    float yv[8];
#pragma unroll
    for (int r = 0; r < 8; ++r) {
        yv[r] = fmaxf(acc[r] + bb, 0.f);
        sy[r][col] = yv[r];
    }
    if (isbf) {
        unsigned short* ob = (unsigned short*)out_raw;
#pragma unroll
        for (int r = 0; r < 8; ++r) ob[(size_t)(r0 + r) * OUTC + col] = f2bf(yv[r]);
    } else {
        float* of = (float*)out_raw;
#pragma unroll
        for (int r = 0; r < 8; ++r) of[(size_t)(r0 + r) * OUTC + col] = yv[r];
    }
    __syncthreads();
    if (tid < 64) {
        const int r = tid >> 3, cap = tid & 7;
        float ss = 0.f;
#pragma unroll
        for (int d = 0; d < 16; ++d) { const float v = sy[r][cap * 16 + d]; ss = fmaf(v, v, ss); }
        sinv[r][cap] = 1.0f / fmaxf(sqrtf(ss), 1e-12f);
    }
    __syncthreads();
#pragma unroll
    for (int r = 0; r < 8; ++r)
        xn[(size_t)(r0 + r) * 128 + col] = sy[r][col] * sinv[r][col >> 4];
}

// ---------------- linear v2: 64 nodes/block, W staged once in LDS (transposed),
// register tile (FOUT/16 outs) x (4 nodes), per-capsule normalize via 16-lane shuffles.
template<int FIN, int FOUT>
__global__ __launch_bounds__(256) void linear_norm_v2(
    const float* __restrict__ xin,
    const float* __restrict__ w,
    const float* __restrict__ bias,
    float* __restrict__ xn,
    const int nnodes)
{
    constexpr int NT = 64;               // nodes per block
    constexpr int KH = FIN / 2;          // two K-phases
    constexpr int NJ = FOUT / 16;        // outs per thread
    constexpr int NTP = NT + 4;          // x stride (mult of 4 for float4)
    constexpr int FOP = FOUT + 1;        // odd stride -> conflict-free transpose
    __shared__ float sx[KH * NTP];       // [k][n]
    __shared__ float sw[KH * FOP];       // [k][o]
    const int tid = threadIdx.x;
    const int othr = tid & 15;           // d-position within capsule
    const int nthr = tid >> 4;           // node group (4 nodes each)
    const int n0 = blockIdx.x * NT;

    float acc[NJ][4];
#pragma unroll
    for (int j = 0; j < NJ; ++j) {
        const float bb = bias[j * 16 + othr];
#pragma unroll
        for (int i = 0; i < 4; ++i) acc[j][i] = bb;
    }

    for (int ph = 0; ph < 2; ++ph) {
        const int kb = ph * KH;
        __syncthreads();   // protect LDS reuse across phases
        // stage x transposed: sx[k][n] = xin[n0+n][kb+k]
        for (int n = nthr; n < NT; n += 16) {
            const int gn = n0 + n;
            for (int k = othr; k < KH; k += 16) {
                float v = 0.f;
                if (gn < nnodes) v = xin[(size_t)gn * FIN + kb + k];
                sx[k * NTP + n] = v;
            }
        }
        // stage w transposed: sw[k][o] = w[o][kb+k]
        for (int o = nthr; o < FOUT; o += 16) {
            for (int k = othr; k < KH; k += 16)
                sw[k * FOP + o] = w[(size_t)o * FIN + kb + k];
        }
        __syncthreads();
#pragma unroll 4
        for (int k = 0; k < KH; ++k) {
            const float4 xv = *(const float4*)&sx[k * NTP + nthr * 4];
#pragma unroll
            for (int j = 0; j < NJ; ++j) {
                const float wv = sw[k * FOP + j * 16 + othr];
                acc[j][0] = fmaf(wv, xv.x, acc[j][0]);
                acc[j][1] = fmaf(wv, xv.y, acc[j][1]);
                acc[j][2] = fmaf(wv, xv.z, acc[j][2]);
                acc[j][3] = fmaf(wv, xv.w, acc[j][3]);
            }
        }
    }

    // per-capsule L2 normalize: capsule j of node n has d-elements spread over
    // the 16 othr lanes (lane = nthr*16+othr within wave -> xor 1,2,4,8 stays in group)
#pragma unroll
    for (int j = 0; j < NJ; ++j) {
#pragma unroll
        for (int i = 0; i < 4; ++i) {
            float ss = acc[j][i] * acc[j][i];
            ss += __shfl_xor(ss, 1);
            ss += __shfl_xor(ss, 2);
            ss += __shfl_xor(ss, 4);
            ss += __shfl_xor(ss, 8);
            acc[j][i] *= 1.0f / fmaxf(sqrtf(ss), 1e-12f);
        }
    }
#pragma unroll
    for (int i = 0; i < 4; ++i) {
        const int gn = n0 + nthr * 4 + i;
        if (gn < nnodes) {
#pragma unroll
            for (int j = 0; j < NJ; ++j)
                xn[(size_t)gn * FOUT + j * 16 + othr] = acc[j][i];
        }
    }
}

// ---------------- routing: one wave per node, z staged in LDS, 5 iterations on-chip.
template<int K>
__global__ __launch_bounds__(64) void routing_kernel(
    const float* __restrict__ xn,
    const int* __restrict__ nb,
    float* __restrict__ xout,
    void* __restrict__ out_raw,
    const int* __restrict__ flag,
    const int coloff)
{
    constexpr int KD16 = K * 16;
    constexpr int ZS = KD16 + 4;          // +4 floats pad -> 2-way banks (free)
    __shared__ float z[16 * ZS];
    __shared__ float u[KD16];
    __shared__ float xs[KD16];
    __shared__ float p[16 * K];
    __shared__ int nid[16];
    const int tid = threadIdx.x;
    const int node = blockIdx.x;
    const bool isbf = (*flag != 0);

    if (tid < 16) nid[tid] = nb[(size_t)node * 16 + tid];
    for (int idx = tid; idx < KD16; idx += 64) {
        const float v = xn[(size_t)node * KD16 + idx];
        xs[idx] = v; u[idx] = v;
    }
    __syncthreads();
    for (int j = 0; j < 16; ++j) {
        const float* src = xn + (size_t)nid[j] * KD16;
        for (int c = tid; c < KD16; c += 64) z[j * ZS + c] = src[c];
    }
    __syncthreads();

    for (int t = 0; t < 5; ++t) {
        for (int idx = tid; idx < 16 * K; idx += 64) {
            const int kk = idx >> 4, j = idx & 15;
            const float4* zp = (const float4*)&z[j * ZS + kk * 16];
            const float4* up = (const float4*)&u[kk * 16];
            float s = 0.f;
#pragma unroll
            for (int g = 0; g < 4; ++g) {
                const float4 a = zp[g], b = up[g];
                s += a.x * b.x + a.y * b.y + a.z * b.z + a.w * b.w;
            }
            p[j * K + kk] = s;
        }
        __syncthreads();
        if (tid < 16) {
            float vals[K];
            float mx = -1e30f;
#pragma unroll
            for (int kk = 0; kk < K; ++kk) { vals[kk] = p[tid * K + kk]; mx = fmaxf(mx, vals[kk]); }
            float s = 0.f;
#pragma unroll
            for (int kk = 0; kk < K; ++kk) { vals[kk] = __expf(vals[kk] - mx); s += vals[kk]; }
            const float inv = 1.0f / s;
#pragma unroll
            for (int kk = 0; kk < K; ++kk) p[tid * K + kk] = vals[kk] * inv;
        }
        __syncthreads();
        if (tid < K * 8) {
            const int kk = tid >> 3, dp = tid & 7, base = kk * 16 + dp * 2;
            float a0 = xs[base], a1 = xs[base + 1];
#pragma unroll
            for (int j = 0; j < 16; ++j) {
                const float pj = p[j * K + kk];
                const float2 zz = *(const float2*)&z[j * ZS + base];
                a0 = fmaf(pj, zz.x, a0);
                a1 = fmaf(pj, zz.y, a1);
            }
            if (t < 4) {
                float ss = a0 * a0 + a1 * a1;
                ss += __shfl_xor(ss, 1);
                ss += __shfl_xor(ss, 2);
                ss += __shfl_xor(ss, 4);
                const float inv = 1.0f / fmaxf(sqrtf(ss), 1e-12f);
                a0 *= inv; a1 *= inv;
                u[base] = a0; u[base + 1] = a1;
            } else {
                a0 = fmaxf(a0, 0.f); a1 = fmaxf(a1, 0.f);
                xout[(size_t)node * KD16 + base]     = a0;
                xout[(size_t)node * KD16 + base + 1] = a1;
                if (isbf) {
                    unsigned short* ob = (unsigned short*)out_raw;
                    const unsigned int packed = ((unsigned int)f2bf(a1) << 16) | (unsigned int)f2bf(a0);
                    *(unsigned int*)&ob[(size_t)node * OUTC + coloff + base] = packed;
                } else {
                    float* of = (float*)out_raw;
                    of[(size_t)node * OUTC + coloff + base]     = a0;
                    of[(size_t)node * OUTC + coloff + base + 1] = a1;
                }
            }
        }
        __syncthreads();
    }
}

extern "C" void kernel_launch(void* const* d_in, const int* in_sizes, int n_in,
                              void* d_out, int out_size, void* d_ws, size_t ws_size,
                              hipStream_t stream) {
    const int* nbid = (const int*)d_in[1];

    int*   flag  = (int*)d_ws;
    float* wblob = (float*)((char*)d_ws + 16);
    float* xn    = (float*)((char*)d_ws + (512 << 10));
    float* xc    = xn + (size_t)NNODES * 128;

    float* pw = wblob +      0; float* pb = wblob +  64000;
    float* w1 = wblob +  64128; float* b1 = wblob +  78464;
    float* w2 = wblob +  78576; float* b2 = wblob +  89328;
    float* w3 = wblob +  89424; float* b3 = wblob +  97104;
    float* w4 = wblob +  97184; float* b4 = wblob + 102304;
    float* w5 = wblob + 102368; float* b5 = wblob + 105440;

    hipLaunchKernelGGL(detect_kernel, dim3(1), dim3(64), 0, stream,
                       (const unsigned short*)d_in[0], flag);

    WPtrs wp;
    for (int i = 0; i < 12; ++i) wp.p[i] = d_in[i + 2];
    hipLaunchKernelGGL(convert_weights, dim3(413), dim3(256), 0, stream, wp, flag, wblob);

    hipLaunchKernelGGL(pca_kernel, dim3(NNODES / 8), dim3(128), 0, stream,
                       d_in[0], pw, pb, flag, xn, d_out);

    const int lingrid = (NNODES + 63) / 64;

    hipLaunchKernelGGL((routing_kernel<8>), dim3(NNODES), dim3(64), 0, stream,
                       xn, nbid, xc, d_out, flag, 128);
    hipLaunchKernelGGL((linear_norm_v2<128, 112>), dim3(lingrid), dim3(256), 0, stream,
                       xc, w1, b1, xn, NNODES);

    hipLaunchKernelGGL((routing_kernel<7>), dim3(NNODES), dim3(64), 0, stream,
                       xn, nbid, xc, d_out, flag, 256);
    hipLaunchKernelGGL((linear_norm_v2<112, 96>), dim3(lingrid), dim3(256), 0, stream,
                       xc, w2, b2, xn, NNODES);

    hipLaunchKernelGGL((routing_kernel<6>), dim3(NNODES), dim3(64), 0, stream,
                       xn, nbid, xc, d_out, flag, 368);
    hipLaunchKernelGGL((linear_norm_v2<96, 80>), dim3(lingrid), dim3(256), 0, stream,
                       xc, w3, b3, xn, NNODES);

    hipLaunchKernelGGL((routing_kernel<5>), dim3(NNODES), dim3(64), 0, stream,
                       xn, nbid, xc, d_out, flag, 464);
    hipLaunchKernelGGL((linear_norm_v2<80, 64>), dim3(lingrid), dim3(256), 0, stream,
                       xc, w4, b4, xn, NNODES);

    hipLaunchKernelGGL((routing_kernel<4>), dim3(NNODES), dim3(64), 0, stream,
                       xn, nbid, xc, d_out, flag, 544);
    hipLaunchKernelGGL((linear_norm_v2<64, 48>), dim3(lingrid), dim3(256), 0, stream,
                       xc, w5, b5, xn, NNODES);

    hipLaunchKernelGGL((routing_kernel<3>), dim3(NNODES), dim3(64), 0, stream,
                       xn, nbid, xc, d_out, flag, 608);
}

// Round 4
// 684.351 us; speedup vs baseline: 1.3937x; 1.1716x over previous
//
#include <hip/hip_runtime.h>
#include <hip/hip_bf16.h>
#include <cstdint>
#include <cstddef>

#define NNODES 20000
#define MNB    16
#define NFEAT  500
#define OUTC   656

typedef short short8 __attribute__((ext_vector_type(8)));
typedef float floatx4 __attribute__((ext_vector_type(4)));

__device__ __forceinline__ float bf2f(unsigned int h) {
    union { unsigned int u; float f; } v; v.u = h << 16; return v.f;
}
__device__ __forceinline__ unsigned short f2bf(float f) {
    union { float f; unsigned int u; } v; v.f = f;
    unsigned int u = v.u;
    u += 0x7FFFu + ((u >> 16) & 1u);   // RNE
    return (unsigned short)(u >> 16);
}

// 16-lane (DPP-row) replicated sum: xor1,xor2 quad_perms + half_mirror + mirror.
template<int CTRL>
__device__ __forceinline__ float dpp_add(float v) {
    const int o = __builtin_amdgcn_mov_dpp(__float_as_int(v), CTRL, 0xF, 0xF, true);
    return v + __int_as_float(o);
}
__device__ __forceinline__ float sum16(float v) {
    v = dpp_add<0xB1>(v);    // quad_perm [1,0,3,2]  == xor 1
    v = dpp_add<0x4E>(v);    // quad_perm [2,3,0,1]  == xor 2
    v = dpp_add<0x141>(v);   // row_half_mirror      == other quad in 8
    v = dpp_add<0x140>(v);   // row_mirror           == other 8 in 16
    return v;
}

__device__ __forceinline__ float dot16(const float4* a, const float4* b) {
    float s = a[0].x * b[0].x;
    s = fmaf(a[0].y, b[0].y, s); s = fmaf(a[0].z, b[0].z, s); s = fmaf(a[0].w, b[0].w, s);
#pragma unroll
    for (int q = 1; q < 4; ++q) {
        s = fmaf(a[q].x, b[q].x, s); s = fmaf(a[q].y, b[q].y, s);
        s = fmaf(a[q].z, b[q].z, s); s = fmaf(a[q].w, b[q].w, s);
    }
    return s;
}

// ---------------- dtype probe
__global__ __launch_bounds__(64) void detect_kernel(const unsigned short* __restrict__ fx,
                                                    int* __restrict__ flag) {
    const int tid = threadIdx.x;
    const unsigned short s = fx[2 * tid];
    const int e = (s >> 7) & 0xFF;
    const bool ok = (e >= 100 && e <= 140);
    const unsigned long long m = __ballot(ok);
    if (tid == 0) *flag = (__popcll(m) >= 32) ? 1 : 0;
}

// ---------------- convert all weights/biases to one fp32 blob in ws
struct WPtrs { const void* p[12]; };

__global__ __launch_bounds__(256) void convert_weights(WPtrs ptrs, const int* __restrict__ flag,
                                                       float* __restrict__ outb) {
    constexpr int SN[12] = {64000,128,14336,112,10752,96,7680,80,5120,64,3072,48};
    constexpr int SO[12] = {0,64000,64128,78464,78576,89328,89424,97104,97184,102304,102368,105440};
    constexpr int TOT = 105488;
    const int i = blockIdx.x * 256 + threadIdx.x;
    if (i >= TOT) return;
    const bool isbf = (*flag != 0);
    int seg = 0, local = i;
#pragma unroll
    for (int s = 0; s < 12; ++s) {
        if (i >= SO[s] && i < SO[s] + SN[s]) { seg = s; local = i - SO[s]; }
    }
    const void* src = ptrs.p[seg];
    float v;
    if (isbf) v = bf2f(((const unsigned short*)src)[local]);
    else      v = ((const float*)src)[local];
    outb[i] = v;
}

// ---------------- pad pca_w (fp32 blob) -> bf16 [128][512] (K-padded with zeros)
__global__ __launch_bounds__(256) void convert_wpad(const float* __restrict__ wblob,
                                                    unsigned short* __restrict__ wpad) {
    const int i = blockIdx.x * 256 + threadIdx.x;   // 128*512 = 65536
    const int n = i >> 9, k = i & 511;
    const float v = (k < NFEAT) ? wblob[n * NFEAT + k] : 0.f;
    wpad[i] = f2bf(v);
}

// ---------------- PCA fp32 fallback (runs only if input is fp32)
__global__ __launch_bounds__(128) void pca_kernel(
    const void* __restrict__ feat_raw,
    const float* __restrict__ wf,
    const float* __restrict__ bf_,
    const int* __restrict__ flag,
    float* __restrict__ xn,
    void* __restrict__ out_raw)
{
    if (*flag != 0) return;   // bf16 path handled by pca_mfma
    __shared__ float sf[8][NFEAT];
    __shared__ float sy[8][129];
    __shared__ float sinv[8][8];
    const int tid = threadIdx.x;
    const int r0 = blockIdx.x * 8;

    const float* feat = (const float*)feat_raw;
    for (int r = 0; r < 8; ++r)
        for (int c = tid; c < NFEAT; c += 128)
            sf[r][c] = feat[(size_t)(r0 + r) * NFEAT + c];
    __syncthreads();

    const int col = tid;
    float acc[8];
#pragma unroll
    for (int r = 0; r < 8; ++r) acc[r] = 0.f;
    const float* wrow = wf + (size_t)col * NFEAT;
    for (int k = 0; k < NFEAT; k += 4) {
        const float4 w4 = *(const float4*)(wrow + k);
#pragma unroll
        for (int r = 0; r < 8; ++r) {
            const float4 f = *(const float4*)&sf[r][k];
            acc[r] = fmaf(w4.x, f.x, acc[r]);
            acc[r] = fmaf(w4.y, f.y, acc[r]);
            acc[r] = fmaf(w4.z, f.z, acc[r]);
            acc[r] = fmaf(w4.w, f.w, acc[r]);
        }
    }
    const float bb = bf_[col];
    float yv[8];
#pragma unroll
    for (int r = 0; r < 8; ++r) {
        yv[r] = fmaxf(acc[r] + bb, 0.f);
        sy[r][col] = yv[r];
    }
    float* of = (float*)out_raw;
#pragma unroll
    for (int r = 0; r < 8; ++r) of[(size_t)(r0 + r) * OUTC + col] = yv[r];
    __syncthreads();
    if (tid < 64) {
        const int r = tid >> 3, cap = tid & 7;
        float ss = 0.f;
#pragma unroll
        for (int d = 0; d < 16; ++d) { const float v = sy[r][cap * 16 + d]; ss = fmaf(v, v, ss); }
        sinv[r][cap] = 1.0f / fmaxf(sqrtf(ss), 1e-12f);
    }
    __syncthreads();
#pragma unroll
    for (int r = 0; r < 8; ++r)
        xn[(size_t)(r0 + r) * 128 + col] = sy[r][col] * sinv[r][col >> 4];
}

// ---------------- PCA via MFMA (bf16 inputs): 64 rows/block, 8 col-tiles, K=512 padded.
__global__ __launch_bounds__(256) void pca_mfma(
    const unsigned short* __restrict__ feat,
    const unsigned short* __restrict__ wpad,   // [128][512] bf16, zero-padded
    const float* __restrict__ bias,
    const int* __restrict__ flag,
    float* __restrict__ xn,
    unsigned short* __restrict__ outb)
{
    if (*flag == 0) return;   // fp32 path handled by pca_kernel
    // stride 56 shorts (112 B): frag-read banks <=2-way, 16B-aligned for b128
    __shared__ short sA[64 * 56];
    __shared__ short sB[128 * 56];
    const int tid = threadIdx.x;
    const int l = tid & 63, wv = tid >> 6;
    const int m = l & 15, q = l >> 4;
    const int r0 = blockIdx.x * 64;

    floatx4 acc[8];
#pragma unroll
    for (int t = 0; t < 8; ++t) acc[t] = 0;

    for (int c = 0; c < 16; ++c) {
        const int k0 = c * 32;
        __syncthreads();
        // stage A: 64 rows x 32 k = 512 uint2 segs (4 shorts each)
#pragma unroll
        for (int it = 0; it < 2; ++it) {
            const int idx = tid + 256 * it;
            const int row = idx >> 3, seg = idx & 7;
            const int grow = r0 + row;
            const int k = k0 + seg * 4;
            uint2 v = make_uint2(0u, 0u);
            if (grow < NNODES && k + 3 < NFEAT)
                v = *(const uint2*)(feat + (size_t)grow * NFEAT + k);
            *(uint2*)&sA[row * 56 + seg * 4] = v;
        }
        // stage B: 128 rows x 32 k = 1024 segs
#pragma unroll
        for (int it = 0; it < 4; ++it) {
            const int idx = tid + 256 * it;
            const int row = idx >> 3, seg = idx & 7;
            const uint2 v = *(const uint2*)(wpad + (size_t)row * 512 + k0 + seg * 4);
            *(uint2*)&sB[row * 56 + seg * 4] = v;
        }
        __syncthreads();
        const short8 af = *(const short8*)&sA[(wv * 16 + m) * 56 + q * 8];
#pragma unroll
        for (int t = 0; t < 8; ++t) {
            const short8 bf = *(const short8*)&sB[(t * 16 + m) * 56 + q * 8];
            acc[t] = __builtin_amdgcn_mfma_f32_16x16x32_bf16(af, bf, acc[t], 0, 0, 0);
        }
    }

    // epilogue: bias + relu -> out[:,0:128] bf16; per-capsule norm -> xn
    float bb[8];
#pragma unroll
    for (int t = 0; t < 8; ++t) bb[t] = bias[t * 16 + m];
#pragma unroll
    for (int t = 0; t < 8; ++t) {
#pragma unroll
        for (int r = 0; r < 4; ++r) {
            const int grow = r0 + wv * 16 + q * 4 + r;   // uniform within DPP row
            if (grow < NNODES) {
                const float y = fmaxf(acc[t][r] + bb[t], 0.f);
                outb[(size_t)grow * OUTC + t * 16 + m] = f2bf(y);
                const float ss = sum16(y * y);
                const float invn = 1.0f / fmaxf(sqrtf(ss), 1e-12f);
                xn[(size_t)grow * 128 + t * 16 + m] = y * invn;
            }
        }
    }
}

// ---------------- linear v2 (unchanged from round 3)
template<int FIN, int FOUT>
__global__ __launch_bounds__(256) void linear_norm_v2(
    const float* __restrict__ xin,
    const float* __restrict__ w,
    const float* __restrict__ bias,
    float* __restrict__ xn,
    const int nnodes)
{
    constexpr int NT = 64;
    constexpr int KH = FIN / 2;
    constexpr int NJ = FOUT / 16;
    constexpr int NTP = NT + 4;
    constexpr int FOP = FOUT + 1;
    __shared__ float sx[KH * NTP];
    __shared__ float sw[KH * FOP];
    const int tid = threadIdx.x;
    const int othr = tid & 15;
    const int nthr = tid >> 4;
    const int n0 = blockIdx.x * NT;

    float acc[NJ][4];
#pragma unroll
    for (int j = 0; j < NJ; ++j) {
        const float bb = bias[j * 16 + othr];
#pragma unroll
        for (int i = 0; i < 4; ++i) acc[j][i] = bb;
    }

    for (int ph = 0; ph < 2; ++ph) {
        const int kb = ph * KH;
        __syncthreads();
        for (int n = nthr; n < NT; n += 16) {
            const int gn = n0 + n;
            for (int k = othr; k < KH; k += 16) {
                float v = 0.f;
                if (gn < nnodes) v = xin[(size_t)gn * FIN + kb + k];
                sx[k * NTP + n] = v;
            }
        }
        for (int o = nthr; o < FOUT; o += 16) {
            for (int k = othr; k < KH; k += 16)
                sw[k * FOP + o] = w[(size_t)o * FIN + kb + k];
        }
        __syncthreads();
#pragma unroll 4
        for (int k = 0; k < KH; ++k) {
            const float4 xv = *(const float4*)&sx[k * NTP + nthr * 4];
#pragma unroll
            for (int j = 0; j < NJ; ++j) {
                const float wv = sw[k * FOP + j * 16 + othr];
                acc[j][0] = fmaf(wv, xv.x, acc[j][0]);
                acc[j][1] = fmaf(wv, xv.y, acc[j][1]);
                acc[j][2] = fmaf(wv, xv.z, acc[j][2]);
                acc[j][3] = fmaf(wv, xv.w, acc[j][3]);
            }
        }
    }
#pragma unroll
    for (int j = 0; j < NJ; ++j) {
#pragma unroll
        for (int i = 0; i < 4; ++i) {
            float ss = acc[j][i] * acc[j][i];
            ss += __shfl_xor(ss, 1);
            ss += __shfl_xor(ss, 2);
            ss += __shfl_xor(ss, 4);
            ss += __shfl_xor(ss, 8);
            acc[j][i] *= 1.0f / fmaxf(sqrtf(ss), 1e-12f);
        }
    }
#pragma unroll
    for (int i = 0; i < 4; ++i) {
        const int gn = n0 + nthr * 4 + i;
        if (gn < nnodes) {
#pragma unroll
            for (int j = 0; j < NJ; ++j)
                xn[(size_t)gn * FOUT + j * 16 + othr] = acc[j][i];
        }
    }
}

// ---------------- routing v2: register-resident, no LDS, no barriers.
// lane: j = l&15 (neighbor), ks = l>>4; slots kk = ks + 4*i.
template<int K>
__global__ __launch_bounds__(256) void routing2(
    const float* __restrict__ xn,
    const int* __restrict__ nb,
    float* __restrict__ xout,
    void* __restrict__ out_raw,
    const int* __restrict__ flag,
    const int coloff)
{
    constexpr int KD16 = K * 16;
    constexpr int NS = (K + 3) / 4;
    const int l = threadIdx.x & 63;
    const int wv = threadIdx.x >> 6;
    const int node = blockIdx.x * 4 + wv;
    const int j = l & 15, ks = l >> 4;
    const bool isbf = (*flag != 0);
    const int nid = nb[(size_t)node * 16 + j];

    float4 z[NS][4], u[NS][4], x16v[NS][4];
#pragma unroll
    for (int i = 0; i < NS; ++i) {
        const int kk = ks + 4 * i;
        const bool valid = (kk < K);
        const float4* zsrc = (const float4*)(xn + (size_t)nid  * KD16 + kk * 16);
        const float4* xsrc = (const float4*)(xn + (size_t)node * KD16 + kk * 16);
#pragma unroll
        for (int q = 0; q < 4; ++q) {
            float4 zq = make_float4(0.f, 0.f, 0.f, 0.f);
            float4 xq = make_float4(0.f, 0.f, 0.f, 0.f);
            if (valid) { zq = zsrc[q]; xq = xsrc[q]; }
            z[i][q] = zq; u[i][q] = xq;
            x16v[i][q] = make_float4(xq.x * 0.0625f, xq.y * 0.0625f,
                                     xq.z * 0.0625f, xq.w * 0.0625f);
        }
    }

    for (int t = 0; t < 5; ++t) {
        // agreement p[j][kk] (in-lane dot16); invalid slots -> -1e30 (exp -> 0)
        float p[NS];
#pragma unroll
        for (int i = 0; i < NS; ++i)
            p[i] = (ks + 4 * i < K) ? dot16(&z[i][0], &u[i][0]) : -1e30f;
        // softmax over all K capsules (cross-ks via shfl 16/32)
        float mx = p[0];
#pragma unroll
        for (int i = 1; i < NS; ++i) mx = fmaxf(mx, p[i]);
        mx = fmaxf(mx, __shfl_xor(mx, 16));
        mx = fmaxf(mx, __shfl_xor(mx, 32));
        float e[NS], s = 0.f;
#pragma unroll
        for (int i = 0; i < NS; ++i) { e[i] = __expf(p[i] - mx); s += e[i]; }
        s += __shfl_xor(s, 16);
        s += __shfl_xor(s, 32);
        const float inv = 1.0f / s;
#pragma unroll
        for (int i = 0; i < NS; ++i) e[i] *= inv;
        // u = sum_j p*z + x  (x folded as x/16 per lane; 16-lane DPP tree)
#pragma unroll
        for (int i = 0; i < NS; ++i) {
#pragma unroll
            for (int q = 0; q < 4; ++q) {
                float4 a;
                a.x = sum16(fmaf(e[i], z[i][q].x, x16v[i][q].x));
                a.y = sum16(fmaf(e[i], z[i][q].y, x16v[i][q].y));
                a.z = sum16(fmaf(e[i], z[i][q].z, x16v[i][q].z));
                a.w = sum16(fmaf(e[i], z[i][q].w, x16v[i][q].w));
                u[i][q] = a;
            }
        }
        if (t < 4) {
#pragma unroll
            for (int i = 0; i < NS; ++i) {
                const float ss = dot16(&u[i][0], &u[i][0]);
                const float invn = 1.0f / fmaxf(sqrtf(ss), 1e-12f);
#pragma unroll
                for (int q = 0; q < 4; ++q) {
                    u[i][q].x *= invn; u[i][q].y *= invn;
                    u[i][q].z *= invn; u[i][q].w *= invn;
                }
            }
        }
    }

    // relu + store (data replicated over 16 j-lanes; lanes j<4 write float4 each)
#pragma unroll
    for (int i = 0; i < NS; ++i) {
#pragma unroll
        for (int q = 0; q < 4; ++q) {
            u[i][q].x = fmaxf(u[i][q].x, 0.f); u[i][q].y = fmaxf(u[i][q].y, 0.f);
            u[i][q].z = fmaxf(u[i][q].z, 0.f); u[i][q].w = fmaxf(u[i][q].w, 0.f);
        }
    }
    if (j < 4) {
#pragma unroll
        for (int i = 0; i < NS; ++i) {
            const int kk = ks + 4 * i;
            if (kk < K) {
                float4 w4 = u[i][0];
                if (j == 1) w4 = u[i][1];
                else if (j == 2) w4 = u[i][2];
                else if (j == 3) w4 = u[i][3];
                *(float4*)(xout + (size_t)node * KD16 + kk * 16 + j * 4) = w4;
                const size_t ooff = (size_t)node * OUTC + coloff + kk * 16 + j * 4;
                if (isbf) {
                    uint2 pk;
                    pk.x = ((unsigned int)f2bf(w4.y) << 16) | f2bf(w4.x);
                    pk.y = ((unsigned int)f2bf(w4.w) << 16) | f2bf(w4.z);
                    *(uint2*)((unsigned short*)out_raw + ooff) = pk;
                } else {
                    *(float4*)((float*)out_raw + ooff) = w4;
                }
            }
        }
    }
}

extern "C" void kernel_launch(void* const* d_in, const int* in_sizes, int n_in,
                              void* d_out, int out_size, void* d_ws, size_t ws_size,
                              hipStream_t stream) {
    const int* nbid = (const int*)d_in[1];

    int*            flag  = (int*)d_ws;
    float*          wblob = (float*)((char*)d_ws + 16);
    unsigned short* wpad  = (unsigned short*)((char*)d_ws + (448 << 10));
    float*          xn    = (float*)((char*)d_ws + (1 << 20));
    float*          xc    = xn + (size_t)NNODES * 128;

    float* pw = wblob +      0; float* pb = wblob +  64000;
    float* w1 = wblob +  64128; float* b1 = wblob +  78464;
    float* w2 = wblob +  78576; float* b2 = wblob +  89328;
    float* w3 = wblob +  89424; float* b3 = wblob +  97104;
    float* w4 = wblob +  97184; float* b4 = wblob + 102304;
    float* w5 = wblob + 102368; float* b5 = wblob + 105440;

    hipLaunchKernelGGL(detect_kernel, dim3(1), dim3(64), 0, stream,
                       (const unsigned short*)d_in[0], flag);

    WPtrs wp;
    for (int i = 0; i < 12; ++i) wp.p[i] = d_in[i + 2];
    hipLaunchKernelGGL(convert_weights, dim3(413), dim3(256), 0, stream, wp, flag, wblob);
    hipLaunchKernelGGL(convert_wpad, dim3(256), dim3(256), 0, stream, pw, wpad);

    // PCA: one of the two runs (flag-predicated)
    hipLaunchKernelGGL(pca_kernel, dim3(NNODES / 8), dim3(128), 0, stream,
                       d_in[0], pw, pb, flag, xn, d_out);
    hipLaunchKernelGGL(pca_mfma, dim3((NNODES + 63) / 64), dim3(256), 0, stream,
                       (const unsigned short*)d_in[0], wpad, pb, flag, xn,
                       (unsigned short*)d_out);

    const int rgrid = NNODES / 4;
    const int lingrid = (NNODES + 63) / 64;

    hipLaunchKernelGGL((routing2<8>), dim3(rgrid), dim3(256), 0, stream,
                       xn, nbid, xc, d_out, flag, 128);
    hipLaunchKernelGGL((linear_norm_v2<128, 112>), dim3(lingrid), dim3(256), 0, stream,
                       xc, w1, b1, xn, NNODES);

    hipLaunchKernelGGL((routing2<7>), dim3(rgrid), dim3(256), 0, stream,
                       xn, nbid, xc, d_out, flag, 256);
    hipLaunchKernelGGL((linear_norm_v2<112, 96>), dim3(lingrid), dim3(256), 0, stream,
                       xc, w2, b2, xn, NNODES);

    hipLaunchKernelGGL((routing2<6>), dim3(rgrid), dim3(256), 0, stream,
                       xn, nbid, xc, d_out, flag, 368);
    hipLaunchKernelGGL((linear_norm_v2<96, 80>), dim3(lingrid), dim3(256), 0, stream,
                       xc, w3, b3, xn, NNODES);

    hipLaunchKernelGGL((routing2<5>), dim3(rgrid), dim3(256), 0, stream,
                       xn, nbid, xc, d_out, flag, 464);
    hipLaunchKernelGGL((linear_norm_v2<80, 64>), dim3(lingrid), dim3(256), 0, stream,
                       xc, w4, b4, xn, NNODES);

    hipLaunchKernelGGL((routing2<4>), dim3(rgrid), dim3(256), 0, stream,
                       xn, nbid, xc, d_out, flag, 544);
    hipLaunchKernelGGL((linear_norm_v2<64, 48>), dim3(lingrid), dim3(256), 0, stream,
                       xc, w5, b5, xn, NNODES);

    hipLaunchKernelGGL((routing2<3>), dim3(rgrid), dim3(256), 0, stream,
                       xn, nbid, xc, d_out, flag, 608);
}

// Round 5
// 597.284 us; speedup vs baseline: 1.5968x; 1.1458x over previous
//
#include <hip/hip_runtime.h>
#include <hip/hip_bf16.h>
#include <cstdint>
#include <cstddef>

#define NNODES 20000
#define MNB    16
#define NFEAT  500
#define OUTC   656

typedef short short8 __attribute__((ext_vector_type(8)));
typedef float floatx4 __attribute__((ext_vector_type(4)));

__device__ __forceinline__ float bf2f(unsigned int h) {
    union { unsigned int u; float f; } v; v.u = h << 16; return v.f;
}
__device__ __forceinline__ unsigned short f2bf(float f) {
    union { float f; unsigned int u; } v; v.f = f;
    unsigned int u = v.u;
    u += 0x7FFFu + ((u >> 16) & 1u);   // RNE
    return (unsigned short)(u >> 16);
}

// 16-lane (DPP-row) replicated sum: xor1,xor2 quad_perms + half_mirror + mirror.
template<int CTRL>
__device__ __forceinline__ float dpp_add(float v) {
    const int o = __builtin_amdgcn_mov_dpp(__float_as_int(v), CTRL, 0xF, 0xF, true);
    return v + __int_as_float(o);
}
__device__ __forceinline__ float sum16(float v) {
    v = dpp_add<0xB1>(v);    // quad_perm xor1
    v = dpp_add<0x4E>(v);    // quad_perm xor2
    v = dpp_add<0x141>(v);   // row_half_mirror
    v = dpp_add<0x140>(v);   // row_mirror
    return v;
}

__device__ __forceinline__ float dot16(const float4* a, const float4* b) {
    float s = a[0].x * b[0].x;
    s = fmaf(a[0].y, b[0].y, s); s = fmaf(a[0].z, b[0].z, s); s = fmaf(a[0].w, b[0].w, s);
#pragma unroll
    for (int q = 1; q < 4; ++q) {
        s = fmaf(a[q].x, b[q].x, s); s = fmaf(a[q].y, b[q].y, s);
        s = fmaf(a[q].z, b[q].z, s); s = fmaf(a[q].w, b[q].w, s);
    }
    return s;
}

// ---------------- dtype probe
__global__ __launch_bounds__(64) void detect_kernel(const unsigned short* __restrict__ fx,
                                                    int* __restrict__ flag) {
    const int tid = threadIdx.x;
    const unsigned short s = fx[2 * tid];
    const int e = (s >> 7) & 0xFF;
    const bool ok = (e >= 100 && e <= 140);
    const unsigned long long m = __ballot(ok);
    if (tid == 0) *flag = (__popcll(m) >= 32) ? 1 : 0;
}

// ---------------- convert all weights/biases to one fp32 blob in ws
struct WPtrs { const void* p[12]; };

__global__ __launch_bounds__(256) void convert_weights(WPtrs ptrs, const int* __restrict__ flag,
                                                       float* __restrict__ outb) {
    constexpr int SN[12] = {64000,128,14336,112,10752,96,7680,80,5120,64,3072,48};
    constexpr int SO[12] = {0,64000,64128,78464,78576,89328,89424,97104,97184,102304,102368,105440};
    constexpr int TOT = 105488;
    const int i = blockIdx.x * 256 + threadIdx.x;
    if (i >= TOT) return;
    const bool isbf = (*flag != 0);
    int seg = 0, local = i;
#pragma unroll
    for (int s = 0; s < 12; ++s) {
        if (i >= SO[s] && i < SO[s] + SN[s]) { seg = s; local = i - SO[s]; }
    }
    const void* src = ptrs.p[seg];
    float v;
    if (isbf) v = bf2f(((const unsigned short*)src)[local]);
    else      v = ((const float*)src)[local];
    outb[i] = v;
}

// ---------------- pad pca_w (fp32 blob) -> bf16 [128][512] (K-padded with zeros)
__global__ __launch_bounds__(256) void convert_wpad(const float* __restrict__ wblob,
                                                    unsigned short* __restrict__ wpad) {
    const int i = blockIdx.x * 256 + threadIdx.x;   // 128*512 = 65536
    const int n = i >> 9, k = i & 511;
    const float v = (k < NFEAT) ? wblob[n * NFEAT + k] : 0.f;
    wpad[i] = f2bf(v);
}

// ---------------- PCA via MFMA (handles fp32 OR bf16 feature; A converted to bf16
// inline during LDS staging). 32 rows/block (20000/32 = 625 blocks), each wave owns
// a 16-row x 64-col quadrant (4 MFMA 16x16x32 tiles), K=512 zero-padded.
__global__ __launch_bounds__(256) void pca_mfma(
    const void* __restrict__ feat_raw,
    const unsigned short* __restrict__ wpad,   // [128][512] bf16
    const float* __restrict__ bias,
    const int* __restrict__ flag,
    float* __restrict__ xn,
    void* __restrict__ out_raw)
{
    __shared__ short sA[32 * 56];   // stride 56 shorts (112 B): 2-way banks = free
    __shared__ short sB[128 * 56];
    const int tid = threadIdx.x;
    const int l = tid & 63, wv = tid >> 6;
    const int m = l & 15, q = l >> 4;
    const int rt = wv >> 1, ch = wv & 1;       // row-tile, col-half
    const int r0 = blockIdx.x * 32;
    const bool isbf = (*flag != 0);

    const int arow = tid >> 3, aseg = tid & 7; // A-stage: 32 rows x 8 segs, 1/thread

    floatx4 acc[4];
#pragma unroll
    for (int t = 0; t < 4; ++t) acc[t] = 0;

    for (int c = 0; c < 16; ++c) {
        const int k0 = c * 32;
        __syncthreads();
        // stage A with inline bf16 conversion
        {
            const int k = k0 + aseg * 4;
            uint2 v = make_uint2(0u, 0u);
            if (k < NFEAT) {   // NFEAT % 4 == 0, so a valid seg is fully valid
                if (isbf) {
                    v = *(const uint2*)((const unsigned short*)feat_raw +
                                        (size_t)(r0 + arow) * NFEAT + k);
                } else {
                    const float4 f = *(const float4*)((const float*)feat_raw +
                                                      (size_t)(r0 + arow) * NFEAT + k);
                    v.x = ((unsigned int)f2bf(f.y) << 16) | f2bf(f.x);
                    v.y = ((unsigned int)f2bf(f.w) << 16) | f2bf(f.z);
                }
            }
            *(uint2*)&sA[arow * 56 + aseg * 4] = v;
        }
        // stage B: 128 rows x 8 segs = 1024, 4/thread (already bf16, padded)
#pragma unroll
        for (int it = 0; it < 4; ++it) {
            const int idx = tid + 256 * it;
            const int row = idx >> 3, seg = idx & 7;
            const uint2 v = *(const uint2*)(wpad + (size_t)row * 512 + k0 + seg * 4);
            *(uint2*)&sB[row * 56 + seg * 4] = v;
        }
        __syncthreads();
        const short8 af = *(const short8*)&sA[(rt * 16 + m) * 56 + q * 8];
#pragma unroll
        for (int t = 0; t < 4; ++t) {
            const short8 bf = *(const short8*)&sB[((ch * 4 + t) * 16 + m) * 56 + q * 8];
            acc[t] = __builtin_amdgcn_mfma_f32_16x16x32_bf16(af, bf, acc[t], 0, 0, 0);
        }
    }

    // epilogue: bias + relu -> out[:,0:128]; per-capsule (16-col) norm -> xn
#pragma unroll
    for (int t = 0; t < 4; ++t) {
        const int col = (ch * 4 + t) * 16 + m;
        const float bb = bias[col];
#pragma unroll
        for (int r = 0; r < 4; ++r) {
            const int grow = r0 + rt * 16 + q * 4 + r;   // always < NNODES (20000%32==0)
            const float y = fmaxf(acc[t][r] + bb, 0.f);
            if (isbf) ((unsigned short*)out_raw)[(size_t)grow * OUTC + col] = f2bf(y);
            else      ((float*)out_raw)[(size_t)grow * OUTC + col] = y;
            const float ss = sum16(y * y);
            const float invn = 1.0f / fmaxf(sqrtf(ss), 1e-12f);
            xn[(size_t)grow * 128 + col] = y * invn;
        }
    }
}

// ---------------- linear v2 (unchanged)
template<int FIN, int FOUT>
__global__ __launch_bounds__(256) void linear_norm_v2(
    const float* __restrict__ xin,
    const float* __restrict__ w,
    const float* __restrict__ bias,
    float* __restrict__ xn,
    const int nnodes)
{
    constexpr int NT = 64;
    constexpr int KH = FIN / 2;
    constexpr int NJ = FOUT / 16;
    constexpr int NTP = NT + 4;
    constexpr int FOP = FOUT + 1;
    __shared__ float sx[KH * NTP];
    __shared__ float sw[KH * FOP];
    const int tid = threadIdx.x;
    const int othr = tid & 15;
    const int nthr = tid >> 4;
    const int n0 = blockIdx.x * NT;

    float acc[NJ][4];
#pragma unroll
    for (int j = 0; j < NJ; ++j) {
        const float bb = bias[j * 16 + othr];
#pragma unroll
        for (int i = 0; i < 4; ++i) acc[j][i] = bb;
    }

    for (int ph = 0; ph < 2; ++ph) {
        const int kb = ph * KH;
        __syncthreads();
        for (int n = nthr; n < NT; n += 16) {
            const int gn = n0 + n;
            for (int k = othr; k < KH; k += 16) {
                float v = 0.f;
                if (gn < nnodes) v = xin[(size_t)gn * FIN + kb + k];
                sx[k * NTP + n] = v;
            }
        }
        for (int o = nthr; o < FOUT; o += 16) {
            for (int k = othr; k < KH; k += 16)
                sw[k * FOP + o] = w[(size_t)o * FIN + kb + k];
        }
        __syncthreads();
#pragma unroll 4
        for (int k = 0; k < KH; ++k) {
            const float4 xv = *(const float4*)&sx[k * NTP + nthr * 4];
#pragma unroll
            for (int j = 0; j < NJ; ++j) {
                const float wv = sw[k * FOP + j * 16 + othr];
                acc[j][0] = fmaf(wv, xv.x, acc[j][0]);
                acc[j][1] = fmaf(wv, xv.y, acc[j][1]);
                acc[j][2] = fmaf(wv, xv.z, acc[j][2]);
                acc[j][3] = fmaf(wv, xv.w, acc[j][3]);
            }
        }
    }
#pragma unroll
    for (int j = 0; j < NJ; ++j) {
#pragma unroll
        for (int i = 0; i < 4; ++i) {
            float ss = acc[j][i] * acc[j][i];
            ss += __shfl_xor(ss, 1);
            ss += __shfl_xor(ss, 2);
            ss += __shfl_xor(ss, 4);
            ss += __shfl_xor(ss, 8);
            acc[j][i] *= 1.0f / fmaxf(sqrtf(ss), 1e-12f);
        }
    }
#pragma unroll
    for (int i = 0; i < 4; ++i) {
        const int gn = n0 + nthr * 4 + i;
        if (gn < nnodes) {
#pragma unroll
            for (int j = 0; j < NJ; ++j)
                xn[(size_t)gn * FOUT + j * 16 + othr] = acc[j][i];
        }
    }
}

// ---------------- routing v2: register-resident, no LDS, no barriers (unchanged)
template<int K>
__global__ __launch_bounds__(256) void routing2(
    const float* __restrict__ xn,
    const int* __restrict__ nb,
    float* __restrict__ xout,
    void* __restrict__ out_raw,
    const int* __restrict__ flag,
    const int coloff)
{
    constexpr int KD16 = K * 16;
    constexpr int NS = (K + 3) / 4;
    const int l = threadIdx.x & 63;
    const int wv = threadIdx.x >> 6;
    const int node = blockIdx.x * 4 + wv;
    const int j = l & 15, ks = l >> 4;
    const bool isbf = (*flag != 0);
    const int nid = nb[(size_t)node * 16 + j];

    float4 z[NS][4], u[NS][4], x16v[NS][4];
#pragma unroll
    for (int i = 0; i < NS; ++i) {
        const int kk = ks + 4 * i;
        const bool valid = (kk < K);
        const float4* zsrc = (const float4*)(xn + (size_t)nid  * KD16 + kk * 16);
        const float4* xsrc = (const float4*)(xn + (size_t)node * KD16 + kk * 16);
#pragma unroll
        for (int q = 0; q < 4; ++q) {
            float4 zq = make_float4(0.f, 0.f, 0.f, 0.f);
            float4 xq = make_float4(0.f, 0.f, 0.f, 0.f);
            if (valid) { zq = zsrc[q]; xq = xsrc[q]; }
            z[i][q] = zq; u[i][q] = xq;
            x16v[i][q] = make_float4(xq.x * 0.0625f, xq.y * 0.0625f,
                                     xq.z * 0.0625f, xq.w * 0.0625f);
        }
    }

    for (int t = 0; t < 5; ++t) {
        float p[NS];
#pragma unroll
        for (int i = 0; i < NS; ++i)
            p[i] = (ks + 4 * i < K) ? dot16(&z[i][0], &u[i][0]) : -1e30f;
        float mx = p[0];
#pragma unroll
        for (int i = 1; i < NS; ++i) mx = fmaxf(mx, p[i]);
        mx = fmaxf(mx, __shfl_xor(mx, 16));
        mx = fmaxf(mx, __shfl_xor(mx, 32));
        float e[NS], s = 0.f;
#pragma unroll
        for (int i = 0; i < NS; ++i) { e[i] = __expf(p[i] - mx); s += e[i]; }
        s += __shfl_xor(s, 16);
        s += __shfl_xor(s, 32);
        const float inv = 1.0f / s;
#pragma unroll
        for (int i = 0; i < NS; ++i) e[i] *= inv;
#pragma unroll
        for (int i = 0; i < NS; ++i) {
#pragma unroll
            for (int q = 0; q < 4; ++q) {
                float4 a;
                a.x = sum16(fmaf(e[i], z[i][q].x, x16v[i][q].x));
                a.y = sum16(fmaf(e[i], z[i][q].y, x16v[i][q].y));
                a.z = sum16(fmaf(e[i], z[i][q].z, x16v[i][q].z));
                a.w = sum16(fmaf(e[i], z[i][q].w, x16v[i][q].w));
                u[i][q] = a;
            }
        }
        if (t < 4) {
#pragma unroll
            for (int i = 0; i < NS; ++i) {
                const float ss = dot16(&u[i][0], &u[i][0]);
                const float invn = 1.0f / fmaxf(sqrtf(ss), 1e-12f);
#pragma unroll
                for (int q = 0; q < 4; ++q) {
                    u[i][q].x *= invn; u[i][q].y *= invn;
                    u[i][q].z *= invn; u[i][q].w *= invn;
                }
            }
        }
    }

#pragma unroll
    for (int i = 0; i < NS; ++i) {
#pragma unroll
        for (int q = 0; q < 4; ++q) {
            u[i][q].x = fmaxf(u[i][q].x, 0.f); u[i][q].y = fmaxf(u[i][q].y, 0.f);
            u[i][q].z = fmaxf(u[i][q].z, 0.f); u[i][q].w = fmaxf(u[i][q].w, 0.f);
        }
    }
    if (j < 4) {
#pragma unroll
        for (int i = 0; i < NS; ++i) {
            const int kk = ks + 4 * i;
            if (kk < K) {
                float4 w4 = u[i][0];
                if (j == 1) w4 = u[i][1];
                else if (j == 2) w4 = u[i][2];
                else if (j == 3) w4 = u[i][3];
                *(float4*)(xout + (size_t)node * KD16 + kk * 16 + j * 4) = w4;
                const size_t ooff = (size_t)node * OUTC + coloff + kk * 16 + j * 4;
                if (isbf) {
                    uint2 pk;
                    pk.x = ((unsigned int)f2bf(w4.y) << 16) | f2bf(w4.x);
                    pk.y = ((unsigned int)f2bf(w4.w) << 16) | f2bf(w4.z);
                    *(uint2*)((unsigned short*)out_raw + ooff) = pk;
                } else {
                    *(float4*)((float*)out_raw + ooff) = w4;
                }
            }
        }
    }
}

extern "C" void kernel_launch(void* const* d_in, const int* in_sizes, int n_in,
                              void* d_out, int out_size, void* d_ws, size_t ws_size,
                              hipStream_t stream) {
    const int* nbid = (const int*)d_in[1];

    int*            flag  = (int*)d_ws;
    float*          wblob = (float*)((char*)d_ws + 16);
    unsigned short* wpad  = (unsigned short*)((char*)d_ws + (448 << 10));
    float*          xn    = (float*)((char*)d_ws + (1 << 20));
    float*          xc    = xn + (size_t)NNODES * 128;

    float* pw = wblob +      0; float* pb = wblob +  64000;
    float* w1 = wblob +  64128; float* b1 = wblob +  78464;
    float* w2 = wblob +  78576; float* b2 = wblob +  89328;
    float* w3 = wblob +  89424; float* b3 = wblob +  97104;
    float* w4 = wblob +  97184; float* b4 = wblob + 102304;
    float* w5 = wblob + 102368; float* b5 = wblob + 105440;

    hipLaunchKernelGGL(detect_kernel, dim3(1), dim3(64), 0, stream,
                       (const unsigned short*)d_in[0], flag);

    WPtrs wp;
    for (int i = 0; i < 12; ++i) wp.p[i] = d_in[i + 2];
    hipLaunchKernelGGL(convert_weights, dim3(413), dim3(256), 0, stream, wp, flag, wblob);
    hipLaunchKernelGGL(convert_wpad, dim3(256), dim3(256), 0, stream, pw, wpad);

    hipLaunchKernelGGL(pca_mfma, dim3(NNODES / 32), dim3(256), 0, stream,
                       d_in[0], wpad, pb, flag, xn, d_out);

    const int rgrid = NNODES / 4;
    const int lingrid = (NNODES + 63) / 64;

    hipLaunchKernelGGL((routing2<8>), dim3(rgrid), dim3(256), 0, stream,
                       xn, nbid, xc, d_out, flag, 128);
    hipLaunchKernelGGL((linear_norm_v2<128, 112>), dim3(lingrid), dim3(256), 0, stream,
                       xc, w1, b1, xn, NNODES);

    hipLaunchKernelGGL((routing2<7>), dim3(rgrid), dim3(256), 0, stream,
                       xn, nbid, xc, d_out, flag, 256);
    hipLaunchKernelGGL((linear_norm_v2<112, 96>), dim3(lingrid), dim3(256), 0, stream,
                       xc, w2, b2, xn, NNODES);

    hipLaunchKernelGGL((routing2<6>), dim3(rgrid), dim3(256), 0, stream,
                       xn, nbid, xc, d_out, flag, 368);
    hipLaunchKernelGGL((linear_norm_v2<96, 80>), dim3(lingrid), dim3(256), 0, stream,
                       xc, w3, b3, xn, NNODES);

    hipLaunchKernelGGL((routing2<5>), dim3(rgrid), dim3(256), 0, stream,
                       xn, nbid, xc, d_out, flag, 464);
    hipLaunchKernelGGL((linear_norm_v2<80, 64>), dim3(lingrid), dim3(256), 0, stream,
                       xc, w4, b4, xn, NNODES);

    hipLaunchKernelGGL((routing2<4>), dim3(rgrid), dim3(256), 0, stream,
                       xn, nbid, xc, d_out, flag, 544);
    hipLaunchKernelGGL((linear_norm_v2<64, 48>), dim3(lingrid), dim3(256), 0, stream,
                       xc, w5, b5, xn, NNODES);

    hipLaunchKernelGGL((routing2<3>), dim3(rgrid), dim3(256), 0, stream,
                       xn, nbid, xc, d_out, flag, 608);
}

// Round 6
// 533.256 us; speedup vs baseline: 1.7886x; 1.1201x over previous
//
#include <hip/hip_runtime.h>
#include <hip/hip_bf16.h>
#include <cstdint>
#include <cstddef>

#define NNODES 20000
#define MNB    16
#define NFEAT  500
#define OUTC   656

typedef short short8 __attribute__((ext_vector_type(8)));
typedef float floatx4 __attribute__((ext_vector_type(4)));

__device__ __forceinline__ float bf2f(unsigned int h) {
    union { unsigned int u; float f; } v; v.u = h << 16; return v.f;
}
__device__ __forceinline__ unsigned short f2bf(float f) {
    union { float f; unsigned int u; } v; v.f = f;
    unsigned int u = v.u;
    u += 0x7FFFu + ((u >> 16) & 1u);   // RNE
    return (unsigned short)(u >> 16);
}

// 16-lane (DPP-row) replicated sum. update_dpp(0,src,...,bound_ctrl=1) is the
// canonical form LLVM folds into a single v_add_f32_dpp.
template<int CTRL>
__device__ __forceinline__ float dpp_add(float v) {
    const int o = __builtin_amdgcn_update_dpp(0, __float_as_int(v), CTRL, 0xF, 0xF, true);
    return v + __int_as_float(o);
}
__device__ __forceinline__ float sum16(float v) {
    v = dpp_add<0xB1>(v);    // quad_perm xor1
    v = dpp_add<0x4E>(v);    // quad_perm xor2
    v = dpp_add<0x141>(v);   // row_half_mirror
    v = dpp_add<0x140>(v);   // row_mirror
    return v;
}

__device__ __forceinline__ float dot16(const float4* a, const float4* b) {
    float s = a[0].x * b[0].x;
    s = fmaf(a[0].y, b[0].y, s); s = fmaf(a[0].z, b[0].z, s); s = fmaf(a[0].w, b[0].w, s);
#pragma unroll
    for (int q = 1; q < 4; ++q) {
        s = fmaf(a[q].x, b[q].x, s); s = fmaf(a[q].y, b[q].y, s);
        s = fmaf(a[q].z, b[q].z, s); s = fmaf(a[q].w, b[q].w, s);
    }
    return s;
}

// ---------------- dtype probe
__global__ __launch_bounds__(64) void detect_kernel(const unsigned short* __restrict__ fx,
                                                    int* __restrict__ flag) {
    const int tid = threadIdx.x;
    const unsigned short s = fx[2 * tid];
    const int e = (s >> 7) & 0xFF;
    const bool ok = (e >= 100 && e <= 140);
    const unsigned long long m = __ballot(ok);
    if (tid == 0) *flag = (__popcll(m) >= 32) ? 1 : 0;
}

// ---------------- convert all weights/biases to one fp32 blob in ws
struct WPtrs { const void* p[12]; };

__global__ __launch_bounds__(256) void convert_weights(WPtrs ptrs, const int* __restrict__ flag,
                                                       float* __restrict__ outb) {
    constexpr int SN[12] = {64000,128,14336,112,10752,96,7680,80,5120,64,3072,48};
    constexpr int SO[12] = {0,64000,64128,78464,78576,89328,89424,97104,97184,102304,102368,105440};
    constexpr int TOT = 105488;
    const int i = blockIdx.x * 256 + threadIdx.x;
    if (i >= TOT) return;
    const bool isbf = (*flag != 0);
    int seg = 0, local = i;
#pragma unroll
    for (int s = 0; s < 12; ++s) {
        if (i >= SO[s] && i < SO[s] + SN[s]) { seg = s; local = i - SO[s]; }
    }
    const void* src = ptrs.p[seg];
    float v;
    if (isbf) v = bf2f(((const unsigned short*)src)[local]);
    else      v = ((const float*)src)[local];
    outb[i] = v;
}

// ---------------- pad pca_w (fp32 blob) -> bf16 [128][512] (K-padded with zeros)
__global__ __launch_bounds__(256) void convert_wpad(const float* __restrict__ wblob,
                                                    unsigned short* __restrict__ wpad) {
    const int i = blockIdx.x * 256 + threadIdx.x;   // 128*512 = 65536
    const int n = i >> 9, k = i & 511;
    const float v = (k < NFEAT) ? wblob[n * NFEAT + k] : 0.f;
    wpad[i] = f2bf(v);
}

// ---------------- PCA via MFMA (fp32 OR bf16 feature; inline bf16 conversion)
__global__ __launch_bounds__(256) void pca_mfma(
    const void* __restrict__ feat_raw,
    const unsigned short* __restrict__ wpad,   // [128][512] bf16
    const float* __restrict__ bias,
    const int* __restrict__ flag,
    float* __restrict__ xn,
    void* __restrict__ out_raw)
{
    __shared__ short sA[32 * 56];   // stride 56 shorts (112 B): 2-way banks = free
    __shared__ short sB[128 * 56];
    const int tid = threadIdx.x;
    const int l = tid & 63, wv = tid >> 6;
    const int m = l & 15, q = l >> 4;
    const int rt = wv >> 1, ch = wv & 1;       // row-tile, col-half
    const int r0 = blockIdx.x * 32;
    const bool isbf = (*flag != 0);

    const int arow = tid >> 3, aseg = tid & 7;

    floatx4 acc[4];
#pragma unroll
    for (int t = 0; t < 4; ++t) acc[t] = 0;

    for (int c = 0; c < 16; ++c) {
        const int k0 = c * 32;
        __syncthreads();
        {
            const int k = k0 + aseg * 4;
            uint2 v = make_uint2(0u, 0u);
            if (k < NFEAT) {
                if (isbf) {
                    v = *(const uint2*)((const unsigned short*)feat_raw +
                                        (size_t)(r0 + arow) * NFEAT + k);
                } else {
                    const float4 f = *(const float4*)((const float*)feat_raw +
                                                      (size_t)(r0 + arow) * NFEAT + k);
                    v.x = ((unsigned int)f2bf(f.y) << 16) | f2bf(f.x);
                    v.y = ((unsigned int)f2bf(f.w) << 16) | f2bf(f.z);
                }
            }
            *(uint2*)&sA[arow * 56 + aseg * 4] = v;
        }
#pragma unroll
        for (int it = 0; it < 4; ++it) {
            const int idx = tid + 256 * it;
            const int row = idx >> 3, seg = idx & 7;
            const uint2 v = *(const uint2*)(wpad + (size_t)row * 512 + k0 + seg * 4);
            *(uint2*)&sB[row * 56 + seg * 4] = v;
        }
        __syncthreads();
        const short8 af = *(const short8*)&sA[(rt * 16 + m) * 56 + q * 8];
#pragma unroll
        for (int t = 0; t < 4; ++t) {
            const short8 bf = *(const short8*)&sB[((ch * 4 + t) * 16 + m) * 56 + q * 8];
            acc[t] = __builtin_amdgcn_mfma_f32_16x16x32_bf16(af, bf, acc[t], 0, 0, 0);
        }
    }

#pragma unroll
    for (int t = 0; t < 4; ++t) {
        const int col = (ch * 4 + t) * 16 + m;
        const float bb = bias[col];
#pragma unroll
        for (int r = 0; r < 4; ++r) {
            const int grow = r0 + rt * 16 + q * 4 + r;
            const float y = fmaxf(acc[t][r] + bb, 0.f);
            if (isbf) ((unsigned short*)out_raw)[(size_t)grow * OUTC + col] = f2bf(y);
            else      ((float*)out_raw)[(size_t)grow * OUTC + col] = y;
            const float ss = sum16(y * y);
            const float invn = 1.0f / fmaxf(sqrtf(ss), 1e-12f);
            xn[(size_t)grow * 128 + col] = y * invn;
        }
    }
}

// ---------------- linear v2 (unchanged)
template<int FIN, int FOUT>
__global__ __launch_bounds__(256) void linear_norm_v2(
    const float* __restrict__ xin,
    const float* __restrict__ w,
    const float* __restrict__ bias,
    float* __restrict__ xn,
    const int nnodes)
{
    constexpr int NT = 64;
    constexpr int KH = FIN / 2;
    constexpr int NJ = FOUT / 16;
    constexpr int NTP = NT + 4;
    constexpr int FOP = FOUT + 1;
    __shared__ float sx[KH * NTP];
    __shared__ float sw[KH * FOP];
    const int tid = threadIdx.x;
    const int othr = tid & 15;
    const int nthr = tid >> 4;
    const int n0 = blockIdx.x * NT;

    float acc[NJ][4];
#pragma unroll
    for (int j = 0; j < NJ; ++j) {
        const float bb = bias[j * 16 + othr];
#pragma unroll
        for (int i = 0; i < 4; ++i) acc[j][i] = bb;
    }

    for (int ph = 0; ph < 2; ++ph) {
        const int kb = ph * KH;
        __syncthreads();
        for (int n = nthr; n < NT; n += 16) {
            const int gn = n0 + n;
            for (int k = othr; k < KH; k += 16) {
                float v = 0.f;
                if (gn < nnodes) v = xin[(size_t)gn * FIN + kb + k];
                sx[k * NTP + n] = v;
            }
        }
        for (int o = nthr; o < FOUT; o += 16) {
            for (int k = othr; k < KH; k += 16)
                sw[k * FOP + o] = w[(size_t)o * FIN + kb + k];
        }
        __syncthreads();
#pragma unroll 4
        for (int k = 0; k < KH; ++k) {
            const float4 xv = *(const float4*)&sx[k * NTP + nthr * 4];
#pragma unroll
            for (int j = 0; j < NJ; ++j) {
                const float wv = sw[k * FOP + j * 16 + othr];
                acc[j][0] = fmaf(wv, xv.x, acc[j][0]);
                acc[j][1] = fmaf(wv, xv.y, acc[j][1]);
                acc[j][2] = fmaf(wv, xv.z, acc[j][2]);
                acc[j][3] = fmaf(wv, xv.w, acc[j][3]);
            }
        }
    }
#pragma unroll
    for (int j = 0; j < NJ; ++j) {
#pragma unroll
        for (int i = 0; i < 4; ++i) {
            float ss = acc[j][i] * acc[j][i];
            ss += __shfl_xor(ss, 1);
            ss += __shfl_xor(ss, 2);
            ss += __shfl_xor(ss, 4);
            ss += __shfl_xor(ss, 8);
            acc[j][i] *= 1.0f / fmaxf(sqrtf(ss), 1e-12f);
        }
    }
#pragma unroll
    for (int i = 0; i < 4; ++i) {
        const int gn = n0 + nthr * 4 + i;
        if (gn < nnodes) {
#pragma unroll
            for (int j = 0; j < NJ; ++j)
                xn[(size_t)gn * FOUT + j * 16 + othr] = acc[j][i];
        }
    }
}

// ---------------- routing v3: register-resident; fused DPP adds; softmax without
// max-subtraction (|p|<=1 since z,u unit-norm per capsule); norm folded into p.
template<int K>
__global__ __launch_bounds__(256) void routing3(
    const float* __restrict__ xn,
    const int* __restrict__ nb,
    float* __restrict__ xout,
    void* __restrict__ out_raw,
    const int* __restrict__ flag,
    const int coloff)
{
    constexpr int KD16 = K * 16;
    constexpr int NS = (K + 3) / 4;
    const int l = threadIdx.x & 63;
    const int wv = threadIdx.x >> 6;
    const int node = blockIdx.x * 4 + wv;
    const int j = l & 15, ks = l >> 4;
    const bool isbf = (*flag != 0);
    const int nid = nb[(size_t)node * 16 + j];

    float4 z[NS][4], u[NS][4], x16v[NS][4];
    float invn[NS];
#pragma unroll
    for (int i = 0; i < NS; ++i) {
        invn[i] = 1.0f;
        const int kk = ks + 4 * i;
        const bool valid = (kk < K);
        const float4* zsrc = (const float4*)(xn + (size_t)nid  * KD16 + kk * 16);
        const float4* xsrc = (const float4*)(xn + (size_t)node * KD16 + kk * 16);
#pragma unroll
        for (int q = 0; q < 4; ++q) {
            float4 zq = make_float4(0.f, 0.f, 0.f, 0.f);
            float4 xq = make_float4(0.f, 0.f, 0.f, 0.f);
            if (valid) { zq = zsrc[q]; xq = xsrc[q]; }
            z[i][q] = zq; u[i][q] = xq;
            x16v[i][q] = make_float4(xq.x * 0.0625f, xq.y * 0.0625f,
                                     xq.z * 0.0625f, xq.w * 0.0625f);
        }
    }

    for (int t = 0; t < 5; ++t) {
        // p = dot(z, u_raw) * invn  (== dot(z, u_hat));  |p| <= 1 -> exp stable
        float e[NS];
        float s = 0.f;
#pragma unroll
        for (int i = 0; i < NS; ++i) {
            const float p = (ks + 4 * i < K) ? dot16(&z[i][0], &u[i][0]) * invn[i] : -1e4f;
            e[i] = __expf(p);
            s += e[i];
        }
        s += __shfl_xor(s, 16);
        s += __shfl_xor(s, 32);
        const float sc = __builtin_amdgcn_rcpf(s);
#pragma unroll
        for (int i = 0; i < NS; ++i) e[i] *= sc;
        // u_raw = sum_j e*z + x  (x folded as x/16 per lane; fused DPP tree)
#pragma unroll
        for (int i = 0; i < NS; ++i) {
#pragma unroll
            for (int q = 0; q < 4; ++q) {
                float4 a;
                a.x = sum16(fmaf(e[i], z[i][q].x, x16v[i][q].x));
                a.y = sum16(fmaf(e[i], z[i][q].y, x16v[i][q].y));
                a.z = sum16(fmaf(e[i], z[i][q].z, x16v[i][q].z));
                a.w = sum16(fmaf(e[i], z[i][q].w, x16v[i][q].w));
                u[i][q] = a;
            }
        }
        if (t < 4) {
#pragma unroll
            for (int i = 0; i < NS; ++i) {
                const float ss = dot16(&u[i][0], &u[i][0]);
                invn[i] = __builtin_amdgcn_rsqf(fmaxf(ss, 1e-24f));
            }
        }
    }

    // relu + store (u replicated over 16 j-lanes; lanes j<4 write float4 each)
#pragma unroll
    for (int i = 0; i < NS; ++i) {
#pragma unroll
        for (int q = 0; q < 4; ++q) {
            u[i][q].x = fmaxf(u[i][q].x, 0.f); u[i][q].y = fmaxf(u[i][q].y, 0.f);
            u[i][q].z = fmaxf(u[i][q].z, 0.f); u[i][q].w = fmaxf(u[i][q].w, 0.f);
        }
    }
    if (j < 4) {
#pragma unroll
        for (int i = 0; i < NS; ++i) {
            const int kk = ks + 4 * i;
            if (kk < K) {
                float4 w4 = u[i][0];
                if (j == 1) w4 = u[i][1];
                else if (j == 2) w4 = u[i][2];
                else if (j == 3) w4 = u[i][3];
                *(float4*)(xout + (size_t)node * KD16 + kk * 16 + j * 4) = w4;
                const size_t ooff = (size_t)node * OUTC + coloff + kk * 16 + j * 4;
                if (isbf) {
                    uint2 pk;
                    pk.x = ((unsigned int)f2bf(w4.y) << 16) | f2bf(w4.x);
                    pk.y = ((unsigned int)f2bf(w4.w) << 16) | f2bf(w4.z);
                    *(uint2*)((unsigned short*)out_raw + ooff) = pk;
                } else {
                    *(float4*)((float*)out_raw + ooff) = w4;
                }
            }
        }
    }
}

extern "C" void kernel_launch(void* const* d_in, const int* in_sizes, int n_in,
                              void* d_out, int out_size, void* d_ws, size_t ws_size,
                              hipStream_t stream) {
    const int* nbid = (const int*)d_in[1];

    int*            flag  = (int*)d_ws;
    float*          wblob = (float*)((char*)d_ws + 16);
    unsigned short* wpad  = (unsigned short*)((char*)d_ws + (448 << 10));
    float*          xn    = (float*)((char*)d_ws + (1 << 20));
    float*          xc    = xn + (size_t)NNODES * 128;

    float* pw = wblob +      0; float* pb = wblob +  64000;
    float* w1 = wblob +  64128; float* b1 = wblob +  78464;
    float* w2 = wblob +  78576; float* b2 = wblob +  89328;
    float* w3 = wblob +  89424; float* b3 = wblob +  97104;
    float* w4 = wblob +  97184; float* b4 = wblob + 102304;
    float* w5 = wblob + 102368; float* b5 = wblob + 105440;

    hipLaunchKernelGGL(detect_kernel, dim3(1), dim3(64), 0, stream,
                       (const unsigned short*)d_in[0], flag);

    WPtrs wp;
    for (int i = 0; i < 12; ++i) wp.p[i] = d_in[i + 2];
    hipLaunchKernelGGL(convert_weights, dim3(413), dim3(256), 0, stream, wp, flag, wblob);
    hipLaunchKernelGGL(convert_wpad, dim3(256), dim3(256), 0, stream, pw, wpad);

    hipLaunchKernelGGL(pca_mfma, dim3(NNODES / 32), dim3(256), 0, stream,
                       d_in[0], wpad, pb, flag, xn, d_out);

    const int rgrid = NNODES / 4;
    const int lingrid = (NNODES + 63) / 64;

    hipLaunchKernelGGL((routing3<8>), dim3(rgrid), dim3(256), 0, stream,
                       xn, nbid, xc, d_out, flag, 128);
    hipLaunchKernelGGL((linear_norm_v2<128, 112>), dim3(lingrid), dim3(256), 0, stream,
                       xc, w1, b1, xn, NNODES);

    hipLaunchKernelGGL((routing3<7>), dim3(rgrid), dim3(256), 0, stream,
                       xn, nbid, xc, d_out, flag, 256);
    hipLaunchKernelGGL((linear_norm_v2<112, 96>), dim3(lingrid), dim3(256), 0, stream,
                       xc, w2, b2, xn, NNODES);

    hipLaunchKernelGGL((routing3<6>), dim3(rgrid), dim3(256), 0, stream,
                       xn, nbid, xc, d_out, flag, 368);
    hipLaunchKernelGGL((linear_norm_v2<96, 80>), dim3(lingrid), dim3(256), 0, stream,
                       xc, w3, b3, xn, NNODES);

    hipLaunchKernelGGL((routing3<5>), dim3(rgrid), dim3(256), 0, stream,
                       xn, nbid, xc, d_out, flag, 464);
    hipLaunchKernelGGL((linear_norm_v2<80, 64>), dim3(lingrid), dim3(256), 0, stream,
                       xc, w4, b4, xn, NNODES);

    hipLaunchKernelGGL((routing3<4>), dim3(rgrid), dim3(256), 0, stream,
                       xn, nbid, xc, d_out, flag, 544);
    hipLaunchKernelGGL((linear_norm_v2<64, 48>), dim3(lingrid), dim3(256), 0, stream,
                       xc, w5, b5, xn, NNODES);

    hipLaunchKernelGGL((routing3<3>), dim3(rgrid), dim3(256), 0, stream,
                       xn, nbid, xc, d_out, flag, 608);
}

// Round 7
// 468.004 us; speedup vs baseline: 2.0379x; 1.1394x over previous
//
#include <hip/hip_runtime.h>
#include <hip/hip_bf16.h>
#include <cstdint>
#include <cstddef>

#define NNODES 20000
#define MNB    16
#define NFEAT  500
#define OUTC   656

typedef short short8 __attribute__((ext_vector_type(8)));
typedef float floatx4 __attribute__((ext_vector_type(4)));

__device__ __forceinline__ float bf2f(unsigned int h) {
    union { unsigned int u; float f; } v; v.u = h << 16; return v.f;
}
__device__ __forceinline__ unsigned short f2bf(float f) {
    union { float f; unsigned int u; } v; v.f = f;
    unsigned int u = v.u;
    u += 0x7FFFu + ((u >> 16) & 1u);   // RNE
    return (unsigned short)(u >> 16);
}

// 16-lane (DPP-row) replicated sum.
template<int CTRL>
__device__ __forceinline__ float dpp_add(float v) {
    const int o = __builtin_amdgcn_update_dpp(0, __float_as_int(v), CTRL, 0xF, 0xF, true);
    return v + __int_as_float(o);
}
__device__ __forceinline__ float sum16(float v) {
    v = dpp_add<0xB1>(v);    // quad_perm xor1
    v = dpp_add<0x4E>(v);    // quad_perm xor2
    v = dpp_add<0x141>(v);   // row_half_mirror
    v = dpp_add<0x140>(v);   // row_mirror
    return v;
}

__device__ __forceinline__ float dot16(const float4* a, const float4* b) {
    float s = a[0].x * b[0].x;
    s = fmaf(a[0].y, b[0].y, s); s = fmaf(a[0].z, b[0].z, s); s = fmaf(a[0].w, b[0].w, s);
#pragma unroll
    for (int q = 1; q < 4; ++q) {
        s = fmaf(a[q].x, b[q].x, s); s = fmaf(a[q].y, b[q].y, s);
        s = fmaf(a[q].z, b[q].z, s); s = fmaf(a[q].w, b[q].w, s);
    }
    return s;
}

// ---------------- dtype probe
__global__ __launch_bounds__(64) void detect_kernel(const unsigned short* __restrict__ fx,
                                                    int* __restrict__ flag) {
    const int tid = threadIdx.x;
    const unsigned short s = fx[2 * tid];
    const int e = (s >> 7) & 0xFF;
    const bool ok = (e >= 100 && e <= 140);
    const unsigned long long m = __ballot(ok);
    if (tid == 0) *flag = (__popcll(m) >= 32) ? 1 : 0;
}

// ---------------- convert all weights/biases to one fp32 blob in ws
struct WPtrs { const void* p[12]; };

__global__ __launch_bounds__(256) void convert_weights(WPtrs ptrs, const int* __restrict__ flag,
                                                       float* __restrict__ outb) {
    constexpr int SN[12] = {64000,128,14336,112,10752,96,7680,80,5120,64,3072,48};
    constexpr int SO[12] = {0,64000,64128,78464,78576,89328,89424,97104,97184,102304,102368,105440};
    constexpr int TOT = 105488;
    const int i = blockIdx.x * 256 + threadIdx.x;
    if (i >= TOT) return;
    const bool isbf = (*flag != 0);
    int seg = 0, local = i;
#pragma unroll
    for (int s = 0; s < 12; ++s) {
        if (i >= SO[s] && i < SO[s] + SN[s]) { seg = s; local = i - SO[s]; }
    }
    const void* src = ptrs.p[seg];
    float v;
    if (isbf) v = bf2f(((const unsigned short*)src)[local]);
    else      v = ((const float*)src)[local];
    outb[i] = v;
}

// ---------------- pad pca_w (fp32 blob) -> bf16 [128][512] (K-padded with zeros)
__global__ __launch_bounds__(256) void convert_wpad(const float* __restrict__ wblob,
                                                    unsigned short* __restrict__ wpad) {
    const int i = blockIdx.x * 256 + threadIdx.x;   // 128*512 = 65536
    const int n = i >> 9, k = i & 511;
    const float v = (k < NFEAT) ? wblob[n * NFEAT + k] : 0.f;
    wpad[i] = f2bf(v);
}

// ---------------- PCA via MFMA (fp32 OR bf16 feature; inline bf16 conversion)
__global__ __launch_bounds__(256) void pca_mfma(
    const void* __restrict__ feat_raw,
    const unsigned short* __restrict__ wpad,   // [128][512] bf16
    const float* __restrict__ bias,
    const int* __restrict__ flag,
    float* __restrict__ xn,
    void* __restrict__ out_raw)
{
    __shared__ short sA[32 * 56];   // stride 56 shorts (112 B): 2-way banks = free
    __shared__ short sB[128 * 56];
    const int tid = threadIdx.x;
    const int l = tid & 63, wv = tid >> 6;
    const int m = l & 15, q = l >> 4;
    const int rt = wv >> 1, ch = wv & 1;       // row-tile, col-half
    const int r0 = blockIdx.x * 32;
    const bool isbf = (*flag != 0);

    const int arow = tid >> 3, aseg = tid & 7;

    floatx4 acc[4];
#pragma unroll
    for (int t = 0; t < 4; ++t) acc[t] = 0;

    for (int c = 0; c < 16; ++c) {
        const int k0 = c * 32;
        __syncthreads();
        {
            const int k = k0 + aseg * 4;
            uint2 v = make_uint2(0u, 0u);
            if (k < NFEAT) {
                if (isbf) {
                    v = *(const uint2*)((const unsigned short*)feat_raw +
                                        (size_t)(r0 + arow) * NFEAT + k);
                } else {
                    const float4 f = *(const float4*)((const float*)feat_raw +
                                                      (size_t)(r0 + arow) * NFEAT + k);
                    v.x = ((unsigned int)f2bf(f.y) << 16) | f2bf(f.x);
                    v.y = ((unsigned int)f2bf(f.w) << 16) | f2bf(f.z);
                }
            }
            *(uint2*)&sA[arow * 56 + aseg * 4] = v;
        }
#pragma unroll
        for (int it = 0; it < 4; ++it) {
            const int idx = tid + 256 * it;
            const int row = idx >> 3, seg = idx & 7;
            const uint2 v = *(const uint2*)(wpad + (size_t)row * 512 + k0 + seg * 4);
            *(uint2*)&sB[row * 56 + seg * 4] = v;
        }
        __syncthreads();
        const short8 af = *(const short8*)&sA[(rt * 16 + m) * 56 + q * 8];
#pragma unroll
        for (int t = 0; t < 4; ++t) {
            const short8 bf = *(const short8*)&sB[((ch * 4 + t) * 16 + m) * 56 + q * 8];
            acc[t] = __builtin_amdgcn_mfma_f32_16x16x32_bf16(af, bf, acc[t], 0, 0, 0);
        }
    }

#pragma unroll
    for (int t = 0; t < 4; ++t) {
        const int col = (ch * 4 + t) * 16 + m;
        const float bb = bias[col];
#pragma unroll
        for (int r = 0; r < 4; ++r) {
            const int grow = r0 + rt * 16 + q * 4 + r;
            const float y = fmaxf(acc[t][r] + bb, 0.f);
            if (isbf) ((unsigned short*)out_raw)[(size_t)grow * OUTC + col] = f2bf(y);
            else      ((float*)out_raw)[(size_t)grow * OUTC + col] = y;
            const float ss = sum16(y * y);
            const float invn = 1.0f / fmaxf(sqrtf(ss), 1e-12f);
            xn[(size_t)grow * 128 + col] = y * invn;
        }
    }
}

// ---------------- linear via MFMA, bf16x3 split precision (~fp32 accuracy).
// 32 nodes/block (grid 625), K-chunks of 32, epilogue fuses bias + capsule norm.
template<int FIN, int FOUT>
__global__ __launch_bounds__(256) void linear_mfma(
    const float* __restrict__ xin,
    const float* __restrict__ w,
    const float* __restrict__ bias,
    float* __restrict__ xn)
{
    constexpr int KP   = ((FIN + 31) / 32) * 32;
    constexpr int NCH  = KP / 32;
    constexpr int NTIL = 2 * (FOUT / 16);
    constexpr int MT   = (NTIL + 3) / 4;
    __shared__ short sAh[32 * 56], sAl[32 * 56];
    __shared__ short sBh[FOUT * 56], sBl[FOUT * 56];
    const int tid = threadIdx.x;
    const int l = tid & 63, wv = tid >> 6;
    const int m = l & 15, q = l >> 4;
    const int n0 = blockIdx.x * 32;

    floatx4 acc[MT];
#pragma unroll
    for (int i = 0; i < MT; ++i) acc[i] = 0;

    for (int c = 0; c < NCH; ++c) {
        const int k0 = c * 32;
        __syncthreads();
        // stage A (x): 32 rows x 8 segs = 256, 1/thread; hi/lo split inline
        {
            const int row = tid >> 3, seg = tid & 7;
            const int k = k0 + seg * 4;
            uint2 vh = make_uint2(0u, 0u), vl = make_uint2(0u, 0u);
            if (k < FIN) {
                const float4 f = *(const float4*)(xin + (size_t)(n0 + row) * FIN + k);
                const unsigned short h0 = f2bf(f.x), h1 = f2bf(f.y);
                const unsigned short h2 = f2bf(f.z), h3 = f2bf(f.w);
                const unsigned short e0 = f2bf(f.x - bf2f(h0)), e1 = f2bf(f.y - bf2f(h1));
                const unsigned short e2 = f2bf(f.z - bf2f(h2)), e3 = f2bf(f.w - bf2f(h3));
                vh = make_uint2(((unsigned)h1 << 16) | h0, ((unsigned)h3 << 16) | h2);
                vl = make_uint2(((unsigned)e1 << 16) | e0, ((unsigned)e3 << 16) | e2);
            }
            *(uint2*)&sAh[row * 56 + seg * 4] = vh;
            *(uint2*)&sAl[row * 56 + seg * 4] = vl;
        }
        // stage B (w): FOUT rows x 8 segs
        for (int idx = tid; idx < FOUT * 8; idx += 256) {
            const int row = idx >> 3, seg = idx & 7;
            const int k = k0 + seg * 4;
            uint2 vh = make_uint2(0u, 0u), vl = make_uint2(0u, 0u);
            if (k < FIN) {
                const float4 f = *(const float4*)(w + (size_t)row * FIN + k);
                const unsigned short h0 = f2bf(f.x), h1 = f2bf(f.y);
                const unsigned short h2 = f2bf(f.z), h3 = f2bf(f.w);
                const unsigned short e0 = f2bf(f.x - bf2f(h0)), e1 = f2bf(f.y - bf2f(h1));
                const unsigned short e2 = f2bf(f.z - bf2f(h2)), e3 = f2bf(f.w - bf2f(h3));
                vh = make_uint2(((unsigned)h1 << 16) | h0, ((unsigned)h3 << 16) | h2);
                vl = make_uint2(((unsigned)e1 << 16) | e0, ((unsigned)e3 << 16) | e2);
            }
            *(uint2*)&sBh[row * 56 + seg * 4] = vh;
            *(uint2*)&sBl[row * 56 + seg * 4] = vl;
        }
        __syncthreads();
#pragma unroll
        for (int ti = 0; ti < MT; ++ti) {
            const int t = wv + ti * 4;
            if (t < NTIL) {
                const int rt = t & 1, ct = t >> 1;
                const int ao = (rt * 16 + m) * 56 + q * 8;
                const int bo = (ct * 16 + m) * 56 + q * 8;
                const short8 ah = *(const short8*)&sAh[ao];
                const short8 al = *(const short8*)&sAl[ao];
                const short8 bh = *(const short8*)&sBh[bo];
                const short8 bl = *(const short8*)&sBl[bo];
                floatx4 a = acc[ti];
                a = __builtin_amdgcn_mfma_f32_16x16x32_bf16(ah, bh, a, 0, 0, 0);
                a = __builtin_amdgcn_mfma_f32_16x16x32_bf16(ah, bl, a, 0, 0, 0);
                a = __builtin_amdgcn_mfma_f32_16x16x32_bf16(al, bh, a, 0, 0, 0);
                acc[ti] = a;
            }
        }
    }
    // epilogue: bias + per-capsule (16-col tile) normalize
#pragma unroll
    for (int ti = 0; ti < MT; ++ti) {
        const int t = wv + ti * 4;
        if (t < NTIL) {
            const int rt = t & 1, ct = t >> 1;
            const int col = ct * 16 + m;
            const float bb = bias[col];
#pragma unroll
            for (int r = 0; r < 4; ++r) {
                const int grow = n0 + rt * 16 + q * 4 + r;
                const float y = acc[ti][r] + bb;
                const float ss = sum16(y * y);
                const float invn = __builtin_amdgcn_rsqf(fmaxf(ss, 1e-24f));
                xn[(size_t)grow * FOUT + col] = y * invn;
            }
        }
    }
}

// ---------------- routing v3 (unchanged from round 6)
template<int K>
__global__ __launch_bounds__(256) void routing3(
    const float* __restrict__ xn,
    const int* __restrict__ nb,
    float* __restrict__ xout,
    void* __restrict__ out_raw,
    const int* __restrict__ flag,
    const int coloff)
{
    constexpr int KD16 = K * 16;
    constexpr int NS = (K + 3) / 4;
    const int l = threadIdx.x & 63;
    const int wv = threadIdx.x >> 6;
    const int node = blockIdx.x * 4 + wv;
    const int j = l & 15, ks = l >> 4;
    const bool isbf = (*flag != 0);
    const int nid = nb[(size_t)node * 16 + j];

    float4 z[NS][4], u[NS][4], x16v[NS][4];
    float invn[NS];
#pragma unroll
    for (int i = 0; i < NS; ++i) {
        invn[i] = 1.0f;
        const int kk = ks + 4 * i;
        const bool valid = (kk < K);
        const float4* zsrc = (const float4*)(xn + (size_t)nid  * KD16 + kk * 16);
        const float4* xsrc = (const float4*)(xn + (size_t)node * KD16 + kk * 16);
#pragma unroll
        for (int q = 0; q < 4; ++q) {
            float4 zq = make_float4(0.f, 0.f, 0.f, 0.f);
            float4 xq = make_float4(0.f, 0.f, 0.f, 0.f);
            if (valid) { zq = zsrc[q]; xq = xsrc[q]; }
            z[i][q] = zq; u[i][q] = xq;
            x16v[i][q] = make_float4(xq.x * 0.0625f, xq.y * 0.0625f,
                                     xq.z * 0.0625f, xq.w * 0.0625f);
        }
    }

    for (int t = 0; t < 5; ++t) {
        float e[NS];
        float s = 0.f;
#pragma unroll
        for (int i = 0; i < NS; ++i) {
            const float p = (ks + 4 * i < K) ? dot16(&z[i][0], &u[i][0]) * invn[i] : -1e4f;
            e[i] = __expf(p);
            s += e[i];
        }
        s += __shfl_xor(s, 16);
        s += __shfl_xor(s, 32);
        const float sc = __builtin_amdgcn_rcpf(s);
#pragma unroll
        for (int i = 0; i < NS; ++i) e[i] *= sc;
#pragma unroll
        for (int i = 0; i < NS; ++i) {
#pragma unroll
            for (int q = 0; q < 4; ++q) {
                float4 a;
                a.x = sum16(fmaf(e[i], z[i][q].x, x16v[i][q].x));
                a.y = sum16(fmaf(e[i], z[i][q].y, x16v[i][q].y));
                a.z = sum16(fmaf(e[i], z[i][q].z, x16v[i][q].z));
                a.w = sum16(fmaf(e[i], z[i][q].w, x16v[i][q].w));
                u[i][q] = a;
            }
        }
        if (t < 4) {
#pragma unroll
            for (int i = 0; i < NS; ++i) {
                const float ss = dot16(&u[i][0], &u[i][0]);
                invn[i] = __builtin_amdgcn_rsqf(fmaxf(ss, 1e-24f));
            }
        }
    }

#pragma unroll
    for (int i = 0; i < NS; ++i) {
#pragma unroll
        for (int q = 0; q < 4; ++q) {
            u[i][q].x = fmaxf(u[i][q].x, 0.f); u[i][q].y = fmaxf(u[i][q].y, 0.f);
            u[i][q].z = fmaxf(u[i][q].z, 0.f); u[i][q].w = fmaxf(u[i][q].w, 0.f);
        }
    }
    if (j < 4) {
#pragma unroll
        for (int i = 0; i < NS; ++i) {
            const int kk = ks + 4 * i;
            if (kk < K) {
                float4 w4 = u[i][0];
                if (j == 1) w4 = u[i][1];
                else if (j == 2) w4 = u[i][2];
                else if (j == 3) w4 = u[i][3];
                *(float4*)(xout + (size_t)node * KD16 + kk * 16 + j * 4) = w4;
                const size_t ooff = (size_t)node * OUTC + coloff + kk * 16 + j * 4;
                if (isbf) {
                    uint2 pk;
                    pk.x = ((unsigned int)f2bf(w4.y) << 16) | f2bf(w4.x);
                    pk.y = ((unsigned int)f2bf(w4.w) << 16) | f2bf(w4.z);
                    *(uint2*)((unsigned short*)out_raw + ooff) = pk;
                } else {
                    *(float4*)((float*)out_raw + ooff) = w4;
                }
            }
        }
    }
}

extern "C" void kernel_launch(void* const* d_in, const int* in_sizes, int n_in,
                              void* d_out, int out_size, void* d_ws, size_t ws_size,
                              hipStream_t stream) {
    const int* nbid = (const int*)d_in[1];

    int*            flag  = (int*)d_ws;
    float*          wblob = (float*)((char*)d_ws + 16);
    unsigned short* wpad  = (unsigned short*)((char*)d_ws + (448 << 10));
    float*          xn    = (float*)((char*)d_ws + (1 << 20));
    float*          xc    = xn + (size_t)NNODES * 128;

    float* pw = wblob +      0; float* pb = wblob +  64000;
    float* w1 = wblob +  64128; float* b1 = wblob +  78464;
    float* w2 = wblob +  78576; float* b2 = wblob +  89328;
    float* w3 = wblob +  89424; float* b3 = wblob +  97104;
    float* w4 = wblob +  97184; float* b4 = wblob + 102304;
    float* w5 = wblob + 102368; float* b5 = wblob + 105440;

    hipLaunchKernelGGL(detect_kernel, dim3(1), dim3(64), 0, stream,
                       (const unsigned short*)d_in[0], flag);

    WPtrs wp;
    for (int i = 0; i < 12; ++i) wp.p[i] = d_in[i + 2];
    hipLaunchKernelGGL(convert_weights, dim3(413), dim3(256), 0, stream, wp, flag, wblob);
    hipLaunchKernelGGL(convert_wpad, dim3(256), dim3(256), 0, stream, pw, wpad);

    hipLaunchKernelGGL(pca_mfma, dim3(NNODES / 32), dim3(256), 0, stream,
                       d_in[0], wpad, pb, flag, xn, d_out);

    const int rgrid = NNODES / 4;
    const int lgrid = NNODES / 32;

    hipLaunchKernelGGL((routing3<8>), dim3(rgrid), dim3(256), 0, stream,
                       xn, nbid, xc, d_out, flag, 128);
    hipLaunchKernelGGL((linear_mfma<128, 112>), dim3(lgrid), dim3(256), 0, stream,
                       xc, w1, b1, xn);

    hipLaunchKernelGGL((routing3<7>), dim3(rgrid), dim3(256), 0, stream,
                       xn, nbid, xc, d_out, flag, 256);
    hipLaunchKernelGGL((linear_mfma<112, 96>), dim3(lgrid), dim3(256), 0, stream,
                       xc, w2, b2, xn);

    hipLaunchKernelGGL((routing3<6>), dim3(rgrid), dim3(256), 0, stream,
                       xn, nbid, xc, d_out, flag, 368);
    hipLaunchKernelGGL((linear_mfma<96, 80>), dim3(lgrid), dim3(256), 0, stream,
                       xc, w3, b3, xn);

    hipLaunchKernelGGL((routing3<5>), dim3(rgrid), dim3(256), 0, stream,
                       xn, nbid, xc, d_out, flag, 464);
    hipLaunchKernelGGL((linear_mfma<80, 64>), dim3(lgrid), dim3(256), 0, stream,
                       xc, w4, b4, xn);

    hipLaunchKernelGGL((routing3<4>), dim3(rgrid), dim3(256), 0, stream,
                       xn, nbid, xc, d_out, flag, 544);
    hipLaunchKernelGGL((linear_mfma<64, 48>), dim3(lgrid), dim3(256), 0, stream,
                       xc, w5, b5, xn);

    hipLaunchKernelGGL((routing3<3>), dim3(rgrid), dim3(256), 0, stream,
                       xn, nbid, xc, d_out, flag, 608);
}